// Round 3
// baseline (715.272 us; speedup 1.0000x reference)
//
#include <hip/hip_runtime.h>
#include <math.h>

#define FIELD 2097152   // 32*512*128
#define NSEQ  4096      // 32*128 sequences

// ---------------------------------------------------------------------------
// 8-point FFT over a lane's 8 register slots (natural-order DFT).
// ---------------------------------------------------------------------------
__device__ __forceinline__ void fft8(float* re, float* im, const bool inv) {
  float y0r = re[0]+re[4], y0i = im[0]+im[4];
  float y1r = re[0]-re[4], y1i = im[0]-im[4];
  float y2r = re[2]+re[6], y2i = im[2]+im[6];
  float y3r = re[2]-re[6], y3i = im[2]-im[6];
  float y4r = re[1]+re[5], y4i = im[1]+im[5];
  float y5r = re[1]-re[5], y5i = im[1]-im[5];
  float y6r = re[3]+re[7], y6i = im[3]+im[7];
  float y7r = re[3]-re[7], y7i = im[3]-im[7];
  float t3r = inv ? -y3i : y3i,  t3i = inv ? y3r : -y3r;
  float t7r = inv ? -y7i : y7i,  t7i = inv ? y7r : -y7r;
  float z0r = y0r+y2r, z0i = y0i+y2i;
  float z2r = y0r-y2r, z2i = y0i-y2i;
  float z1r = y1r+t3r, z1i = y1i+t3i;
  float z3r = y1r-t3r, z3i = y1i-t3i;
  float z4r = y4r+y6r, z4i = y4i+y6i;
  float z6r = y4r-y6r, z6i = y4i-y6i;
  float z5r = y5r+t7r, z5i = y5i+t7i;
  float z7r = y5r-t7r, z7i = y5i-t7i;
  const float R = 0.70710678118654752440f;
  const float s = inv ? R : -R;
  float a5r = R*z5r - s*z5i, a5i = R*z5i + s*z5r;
  float a6r = inv ? -z6i : z6i, a6i = inv ? z6r : -z6r;
  float a7r = -R*z7r - s*z7i, a7i = -R*z7i + s*z7r;
  re[0] = z0r+z4r; im[0] = z0i+z4i;
  re[4] = z0r-z4r; im[4] = z0i-z4i;
  re[1] = z1r+a5r; im[1] = z1i+a5i;
  re[5] = z1r-a5r; im[5] = z1i-a5i;
  re[2] = z2r+a6r; im[2] = z2i+a6i;
  re[6] = z2r-a6r; im[6] = z2i-a6i;
  re[3] = z3r+a7r; im[3] = z3i+a7i;
  re[7] = z3r-a7r; im[7] = z3i-a7i;
}

// 64-point FFT across lanes (radix-2, 6 stages of shfl_xor).
__device__ __forceinline__ void fft64_fwd(float* vr, float* vi,
                                          const float* Wr, const float* Wi,
                                          int lane) {
#pragma unroll
  for (int s = 0; s < 6; ++s) {
    const int h = 32 >> s;
    const bool hi = (lane & h) != 0;
    const float sg = hi ? -1.0f : 1.0f;
#pragma unroll
    for (int b = 0; b < 8; ++b) {
      float pr = __shfl_xor(vr[b], h, 64);
      float pi = __shfl_xor(vi[b], h, 64);
      float tr = fmaf(sg, vr[b], pr);
      float ti = fmaf(sg, vi[b], pi);
      float mr = tr * Wr[s] - ti * Wi[s];
      float mi = tr * Wi[s] + ti * Wr[s];
      vr[b] = hi ? mr : tr;
      vi[b] = hi ? mi : ti;
    }
  }
}

__device__ __forceinline__ void fft64_inv(float* vr, float* vi,
                                          const float* Wr, const float* Wi,
                                          int lane) {
#pragma unroll
  for (int s = 5; s >= 0; --s) {
    const int h = 32 >> s;
    const bool hi = (lane & h) != 0;
    const float sg = hi ? -1.0f : 1.0f;
#pragma unroll
    for (int b = 0; b < 8; ++b) {
      float pr = __shfl_xor(vr[b], h, 64);
      float pi = __shfl_xor(vi[b], h, 64);
      float qr = hi ? vr[b] : pr;
      float qi = hi ? vi[b] : pi;
      float rr = hi ? pr : vr[b];
      float ri = hi ? pi : vi[b];
      float tr = fmaf(Wr[s], qr,  Wi[s] * qi);
      float ti = fmaf(Wr[s], qi, -(Wi[s] * qr));
      vr[b] = fmaf(sg, tr, rr);
      vi[b] = fmaf(sg, ti, ri);
    }
  }
}

__device__ __forceinline__ void fft512_fwd(float* vr, float* vi,
                                           const float* twFr, const float* twFi,
                                           const float* Wr, const float* Wi,
                                           int lane) {
  fft8(vr, vi, false);
#pragma unroll
  for (int b = 1; b < 8; ++b) {
    float ar = vr[b], ai = vi[b];
    vr[b] = ar * twFr[b] - ai * twFi[b];
    vi[b] = ar * twFi[b] + ai * twFr[b];
  }
  fft64_fwd(vr, vi, Wr, Wi, lane);
}

__device__ __forceinline__ void fft512_inv(float* vr, float* vi,
                                           const float* twFr, const float* twFi,
                                           const float* Wr, const float* Wi,
                                           int lane) {
  fft64_inv(vr, vi, Wr, Wi, lane);
#pragma unroll
  for (int b = 1; b < 8; ++b) {
    float ar = vr[b], ai = vi[b];
    vr[b] = ar * twFr[b] + ai * twFi[b];
    vi[b] = ai * twFr[b] - ar * twFi[b];
  }
  fft8(vr, vi, true);
}

__device__ __forceinline__ void mode_update(const float* Xr, const float* Xi,
                                            const float* Vr, const float* Vi,
                                            float* Ur, float* Ui,
                                            const float* lamF, float om,
                                            float fbase, int pl0, int plx) {
  float Tr[8], Ti[8];
#pragma unroll
  for (int b = 0; b < 8; ++b) {
    float fb = fbase + (float)b * (1.0f / 512.0f);
    float df = fb - om;
    float den = __builtin_amdgcn_rcpf(fmaf(1600.0f * df, df, 1.0f));
    Tr[b] = (Xr[b] - Vr[b] + 0.5f * lamF[b]) * den;
    Ti[b] = (Xi[b] - Vi[b]) * den;
  }
#pragma unroll
  for (int b = 0; b < 8; ++b) {
    const int pb = (8 - b) & 7;
    const int pl = (b == 0) ? pl0 : plx;
    float sr = __shfl(Tr[pb], pl, 64);
    float si = __shfl(Ti[pb], pl, 64);
    Ur[b] = 0.5f * (Tr[b] + sr);
    Ui[b] = 0.5f * (Ti[b] - si);
  }
}

// One wave per (b,d) sequence; 4 waves/block covering 4 consecutive d.
// Global I/O staged through LDS as float4 (coalesced); XCD swizzle keeps the
// 4 blocks sharing each 64B line-group on one XCD (L2 absorbs the 4x reuse).
__global__ __launch_bounds__(256, 4) void vmd_kernel(const float* __restrict__ x,
                                                     float* __restrict__ out) {
  __shared__ float stage[4 * 512];    // [seq][n] transpose buffer (in & out)
  __shared__ float ldsLam[4 * 576];   // stride-9 permuted lambda per wave

  const int tid = threadIdx.x;
  const int wv = tid >> 6;
  const int lane = tid & 63;
  // blockIdx%8 -> XCD (heuristic): consecutive w on same XCD.
  const int w = (blockIdx.x >> 3) + ((blockIdx.x & 7) << 7);   // 0..1023
  const int g = 4 * w + wv;           // sequence id 0..4095
  const int bb = w >> 5;              // batch 0..31
  const int d0 = (4 * w) & 127;       // 4-aligned d of this block
  const int base4 = bb * 16384 + (d0 >> 2);   // float4 index of (bb,0,d0)
  float* lamLds = ldsLam + wv * 576;

  const int rev = (int)(__brev((unsigned)lane) >> 26);   // rev6(lane)
  const int m0 = rev << 3;
  const bool pos = (lane & 1) == 0;                       // m < 256
  const float pm = pos ? 1.0f : 0.0f;
  const float fbase = (float)(m0 - (pos ? 0 : 512)) * (1.0f / 512.0f);
  const int plx = lane ^ 63;
  const int pl0 = (int)(__brev((unsigned)((64 - rev) & 63)) >> 26);
  const int h3 = lane >> 3;
  const int rev3h = ((h3 & 1) << 2) | (h3 & 2) | ((h3 >> 2) & 1);
  const int wbase = 9 * (rev3h << 3) + (lane & 7);
  const int caOff[8] = {9, 45, 27, 63, 0, 36, 18, 54};

  float Wr[6], Wi[6];
#pragma unroll
  for (int s = 0; s < 6; ++s) {
    const int h = 32 >> s;
    float th = (float)(lane & (h - 1)) * (3.14159265358979323846f / (float)h);
    float sn, cs;
    sincosf(th, &sn, &cs);
    Wr[s] = cs; Wi[s] = -sn;
  }
  float twFr[8], twFi[8];
  twFr[0] = 1.0f; twFi[0] = 0.0f;
#pragma unroll
  for (int b = 1; b < 8; ++b) {
    float th = (float)(lane * b) * 0.01227184630308513f;
    float sn, cs;
    sincosf(th, &sn, &cs);
    twFr[b] = cs; twFi[b] = -sn;
  }

  // ---- coalesced load: float4 (n, d0..d0+3) -> stage[seq][n] ----
  {
    const float4* x4 = (const float4*)x;
    float4 va = x4[base4 + tid * 32];
    float4 vb = x4[base4 + (tid + 256) * 32];
    stage[tid]        = va.x; stage[512 + tid]        = va.y;
    stage[1024 + tid] = va.z; stage[1536 + tid]       = va.w;
    stage[tid + 256]        = vb.x; stage[512 + tid + 256]  = vb.y;
    stage[1024 + tid + 256] = vb.z; stage[1536 + tid + 256] = vb.w;
  }
  __syncthreads();

  float xT[8], Xr[8], Xi[8];
#pragma unroll
  for (int a = 0; a < 8; ++a) {
    float xv = stage[wv * 512 + a * 64 + lane];
    xT[a] = xv; Xr[a] = xv; Xi[a] = 0.0f;
  }
  fft512_fwd(Xr, Xi, twFr, twFi, Wr, Wi, lane);

  float U0r[8], U0i[8], U1r[8], U1i[8], lamW[8], lamF[8];
#pragma unroll
  for (int b = 0; b < 8; ++b) {
    U0r[b] = 0.0f; U0i[b] = 0.0f; U1r[b] = 0.0f; U1i[b] = 0.0f;
    lamW[b] = 0.0f; lamF[b] = 0.0f;
  }
  float om0 = 0.0f, om1 = 0.0f;

#pragma unroll 1
  for (int it = 0; it < 50; ++it) {
    mode_update(Xr, Xi, U1r, U1i, U0r, U0i, lamF, om0, fbase, pl0, plx);
    mode_update(Xr, Xi, U0r, U0i, U1r, U1i, lamF, om1, fbase, pl0, plx);

    float n0 = 0.0f, d0s = 0.0f, n1 = 0.0f, d1 = 0.0f;
#pragma unroll
    for (int b = 0; b < 8; ++b) {
      float f = fbase + (float)b * (1.0f / 512.0f);
      float p0 = U0r[b] * U0r[b] + U0i[b] * U0i[b];
      float p1 = U1r[b] * U1r[b] + U1i[b] * U1i[b];
      n0 = fmaf(f, p0, n0); d0s += p0;
      n1 = fmaf(f, p1, n1); d1 += p1;
    }
    n0 *= pm; d0s *= pm; n1 *= pm; d1 *= pm;
#pragma unroll
    for (int off = 32; off >= 1; off >>= 1) {
      n0 += __shfl_xor(n0, off, 64);
      d0s += __shfl_xor(d0s, off, 64);
      n1 += __shfl_xor(n1, off, 64);
      d1 += __shfl_xor(d1, off, 64);
    }
    om0 = n0 / (d0s + 1e-7f);
    om1 = n1 / (d1 + 1e-7f);

    if (it < 49) {   // last iteration's lambda is never consumed
      float Sr[8], Si[8];
#pragma unroll
      for (int b = 0; b < 8; ++b) { Sr[b] = U0r[b] + U1r[b]; Si[b] = U0i[b] + U1i[b]; }
      fft512_inv(Sr, Si, twFr, twFi, Wr, Wi, lane);
#pragma unroll
      for (int a = 0; a < 8; ++a)
        lamW[a] = fmaf(0.001f, xT[a] - Sr[a] * (1.0f / 512.0f), lamW[a]);
#pragma unroll
      for (int a = 0; a < 8; ++a) lamLds[wbase + caOff[a]] = lamW[a];
      asm volatile("s_waitcnt lgkmcnt(0)" ::: "memory");
#pragma unroll
      for (int b = 0; b < 8; ++b) lamF[b] = lamLds[9 * lane + b];
    }
  }

  // ---- final modes: ifft -> stage[seq][n] -> coalesced float4 stores ----
  float4* o4 = (float4*)out;
  {
    float Sr[8], Si[8];
#pragma unroll
    for (int b = 0; b < 8; ++b) { Sr[b] = U0r[b]; Si[b] = U0i[b]; }
    fft512_inv(Sr, Si, twFr, twFi, Wr, Wi, lane);
#pragma unroll
    for (int a = 0; a < 8; ++a)
      stage[wv * 512 + a * 64 + lane] = Sr[a] * (1.0f / 512.0f);
  }
  __syncthreads();
#pragma unroll
  for (int r = 0; r < 2; ++r) {
    const int n = tid + r * 256;
    float4 v;
    v.x = stage[n]; v.y = stage[512 + n]; v.z = stage[1024 + n]; v.w = stage[1536 + n];
    o4[FIELD / 4 + base4 + n * 32] = v;
  }
  __syncthreads();
  {
    float Sr[8], Si[8];
#pragma unroll
    for (int b = 0; b < 8; ++b) { Sr[b] = U1r[b]; Si[b] = U1i[b]; }
    fft512_inv(Sr, Si, twFr, twFi, Wr, Wi, lane);
#pragma unroll
    for (int a = 0; a < 8; ++a)
      stage[wv * 512 + a * 64 + lane] = Sr[a] * (1.0f / 512.0f);
  }
  __syncthreads();
#pragma unroll
  for (int r = 0; r < 2; ++r) {
    const int n = tid + r * 256;
    float4 v;
    v.x = stage[n]; v.y = stage[512 + n]; v.z = stage[1024 + n]; v.w = stage[1536 + n];
    o4[2 * FIELD / 4 + base4 + n * 32] = v;
  }

  if (lane == 0) {
    out[g] = om0;            // staged in trend region (zeroed later)
    out[NSEQ + g] = om1;
  }
}

__global__ __launch_bounds__(128) void order_kernel(float* __restrict__ out) {
  const int bb = blockIdx.x;
  const int dd = threadIdx.x;
  float o0 = out[bb * 128 + dd];
  float o1 = out[NSEQ + bb * 128 + dd];
#pragma unroll
  for (int off = 32; off >= 1; off >>= 1) {
    o0 += __shfl_down(o0, off);
    o1 += __shfl_down(o1, off);
  }
  __shared__ float s0[2], s1[2];
  const int wv = dd >> 6;
  if ((dd & 63) == 0) { s0[wv] = o0; s1[wv] = o1; }
  __syncthreads();
  if (dd == 0) {
    const float a = s0[0] + s0[1];
    const float c = s1[0] + s1[1];
    out[2 * NSEQ + bb] = (a > c) ? 1.0f : 0.0f;
  }
}

__global__ __launch_bounds__(256) void swap_kernel(float* __restrict__ out) {
  const int idx = blockIdx.x * 256 + threadIdx.x;
  const int bb = idx >> 16;
  const float flag = out[2 * NSEQ + bb];
  if (flag > 0.5f) {
    const float p = out[FIELD + idx];
    const float r = out[2 * FIELD + idx];
    out[FIELD + idx] = r;
    out[2 * FIELD + idx] = p;
  }
}

extern "C" void kernel_launch(void* const* d_in, const int* in_sizes, int n_in,
                              void* d_out, int out_size, void* d_ws, size_t ws_size,
                              hipStream_t stream) {
  (void)in_sizes; (void)n_in; (void)d_ws; (void)ws_size; (void)out_size;
  const float* x = (const float*)d_in[0];
  float* out = (float*)d_out;
  vmd_kernel<<<NSEQ / 4, 256, 0, stream>>>(x, out);
  order_kernel<<<32, 128, 0, stream>>>(out);
  swap_kernel<<<FIELD / 256, 256, 0, stream>>>(out);
  hipMemsetAsync(out, 0, (size_t)FIELD * sizeof(float), stream);
}

// Round 4
// 603.449 us; speedup vs baseline: 1.1853x; 1.1853x over previous
//
#include <hip/hip_runtime.h>
#include <math.h>

#define FIELD 2097152   // 32*512*128
#define NSEQ  4096      // 32*128 sequences

// ---------------------------------------------------------------------------
// 8-point FFT over a lane's 8 register slots (natural-order DFT).
// ---------------------------------------------------------------------------
__device__ __forceinline__ void fft8(float* re, float* im, const bool inv) {
  float y0r = re[0]+re[4], y0i = im[0]+im[4];
  float y1r = re[0]-re[4], y1i = im[0]-im[4];
  float y2r = re[2]+re[6], y2i = im[2]+im[6];
  float y3r = re[2]-re[6], y3i = im[2]-im[6];
  float y4r = re[1]+re[5], y4i = im[1]+im[5];
  float y5r = re[1]-re[5], y5i = im[1]-im[5];
  float y6r = re[3]+re[7], y6i = im[3]+im[7];
  float y7r = re[3]-re[7], y7i = im[3]-im[7];
  float t3r = inv ? -y3i : y3i,  t3i = inv ? y3r : -y3r;
  float t7r = inv ? -y7i : y7i,  t7i = inv ? y7r : -y7r;
  float z0r = y0r+y2r, z0i = y0i+y2i;
  float z2r = y0r-y2r, z2i = y0i-y2i;
  float z1r = y1r+t3r, z1i = y1i+t3i;
  float z3r = y1r-t3r, z3i = y1i-t3i;
  float z4r = y4r+y6r, z4i = y4i+y6i;
  float z6r = y4r-y6r, z6i = y4i-y6i;
  float z5r = y5r+t7r, z5i = y5i+t7i;
  float z7r = y5r-t7r, z7i = y5i-t7i;
  const float R = 0.70710678118654752440f;
  const float s = inv ? R : -R;
  float a5r = R*z5r - s*z5i, a5i = R*z5i + s*z5r;
  float a6r = inv ? -z6i : z6i, a6i = inv ? z6r : -z6r;
  float a7r = -R*z7r - s*z7i, a7i = -R*z7i + s*z7r;
  re[0] = z0r+z4r; im[0] = z0i+z4i;
  re[4] = z0r-z4r; im[4] = z0i-z4i;
  re[1] = z1r+a5r; im[1] = z1i+a5i;
  re[5] = z1r-a5r; im[5] = z1i-a5i;
  re[2] = z2r+a6r; im[2] = z2i+a6i;
  re[6] = z2r-a6r; im[6] = z2i-a6i;
  re[3] = z3r+a7r; im[3] = z3i+a7i;
  re[7] = z3r-a7r; im[7] = z3i-a7i;
}

// 64-point FFT across lanes (radix-2, 6 stages of shfl_xor).
__device__ __forceinline__ void fft64_fwd(float* vr, float* vi,
                                          const float* Wr, const float* Wi,
                                          int lane) {
#pragma unroll
  for (int s = 0; s < 6; ++s) {
    const int h = 32 >> s;
    const bool hi = (lane & h) != 0;
    const float sg = hi ? -1.0f : 1.0f;
#pragma unroll
    for (int b = 0; b < 8; ++b) {
      float pr = __shfl_xor(vr[b], h, 64);
      float pi = __shfl_xor(vi[b], h, 64);
      float tr = fmaf(sg, vr[b], pr);
      float ti = fmaf(sg, vi[b], pi);
      float mr = tr * Wr[s] - ti * Wi[s];
      float mi = tr * Wi[s] + ti * Wr[s];
      vr[b] = hi ? mr : tr;
      vi[b] = hi ? mi : ti;
    }
  }
}

__device__ __forceinline__ void fft64_inv(float* vr, float* vi,
                                          const float* Wr, const float* Wi,
                                          int lane) {
#pragma unroll
  for (int s = 5; s >= 0; --s) {
    const int h = 32 >> s;
    const bool hi = (lane & h) != 0;
    const float sg = hi ? -1.0f : 1.0f;
#pragma unroll
    for (int b = 0; b < 8; ++b) {
      float pr = __shfl_xor(vr[b], h, 64);
      float pi = __shfl_xor(vi[b], h, 64);
      float qr = hi ? vr[b] : pr;
      float qi = hi ? vi[b] : pi;
      float rr = hi ? pr : vr[b];
      float ri = hi ? pi : vi[b];
      float tr = fmaf(Wr[s], qr,  Wi[s] * qi);
      float ti = fmaf(Wr[s], qi, -(Wi[s] * qr));
      vr[b] = fmaf(sg, tr, rr);
      vi[b] = fmaf(sg, ti, ri);
    }
  }
}

__device__ __forceinline__ void fft512_fwd(float* vr, float* vi,
                                           const float* twFr, const float* twFi,
                                           const float* Wr, const float* Wi,
                                           int lane) {
  fft8(vr, vi, false);
#pragma unroll
  for (int b = 1; b < 8; ++b) {
    float ar = vr[b], ai = vi[b];
    vr[b] = ar * twFr[b] - ai * twFi[b];
    vi[b] = ar * twFi[b] + ai * twFr[b];
  }
  fft64_fwd(vr, vi, Wr, Wi, lane);
}

__device__ __forceinline__ void fft512_inv(float* vr, float* vi,
                                           const float* twFr, const float* twFi,
                                           const float* Wr, const float* Wi,
                                           int lane) {
  fft64_inv(vr, vi, Wr, Wi, lane);
#pragma unroll
  for (int b = 1; b < 8; ++b) {
    float ar = vr[b], ai = vi[b];
    vr[b] = ar * twFr[b] + ai * twFi[b];
    vi[b] = ai * twFr[b] - ar * twFi[b];
  }
  fft8(vr, vi, true);
}

__device__ __forceinline__ void mode_update(const float* Xr, const float* Xi,
                                            const float* Vr, const float* Vi,
                                            float* Ur, float* Ui,
                                            const float* lamF, float om,
                                            float fbase, int pl0, int plx) {
  float Tr[8], Ti[8];
#pragma unroll
  for (int b = 0; b < 8; ++b) {
    float fb = fbase + (float)b * (1.0f / 512.0f);
    float df = fb - om;
    float den = __builtin_amdgcn_rcpf(fmaf(1600.0f * df, df, 1.0f));
    Tr[b] = (Xr[b] - Vr[b] + 0.5f * lamF[b]) * den;
    Ti[b] = (Xi[b] - Vi[b]) * den;
  }
#pragma unroll
  for (int b = 0; b < 8; ++b) {
    const int pb = (8 - b) & 7;
    const int pl = (b == 0) ? pl0 : plx;
    float sr = __shfl(Tr[pb], pl, 64);
    float si = __shfl(Ti[pb], pl, 64);
    Ur[b] = 0.5f * (Tr[b] + sr);
    Ui[b] = 0.5f * (Ti[b] - si);
  }
}

// One wave per (b,d) sequence; 4 waves/block covering 4 consecutive d.
// launch_bounds(256,3): VGPR cap ~168 so the full iteration state stays
// register-resident (round 3's 64-VGPR build spilled ~36 floats/iter to
// scratch -> 1.9 GB HBM fetch). x stays in LDS; everything else in regs.
__global__ __launch_bounds__(256, 3) void vmd_kernel(const float* __restrict__ x,
                                                     float* __restrict__ out) {
  __shared__ float stage[4 * 512];    // [seq][n]; x resident during loop, reused for out
  __shared__ float ldsLam[4 * 576];   // stride-9 permuted lambda per wave

  const int tid = threadIdx.x;
  const int wv = tid >> 6;
  const int lane = tid & 63;
  // blockIdx%8 -> XCD (heuristic): consecutive w on same XCD.
  const int w = (blockIdx.x >> 3) + ((blockIdx.x & 7) << 7);   // 0..1023
  const int g = 4 * w + wv;           // sequence id 0..4095
  const int bb = w >> 5;              // batch 0..31
  const int d0 = (4 * w) & 127;       // 4-aligned d of this block
  const int base4 = bb * 16384 + (d0 >> 2);   // float4 index of (bb,0,d0)
  float* lamLds = ldsLam + wv * 576;

  const int rev = (int)(__brev((unsigned)lane) >> 26);   // rev6(lane)
  const int m0 = rev << 3;
  const bool pos = (lane & 1) == 0;                       // m < 256
  const float pm = pos ? 1.0f : 0.0f;
  const float fbase = (float)(m0 - (pos ? 0 : 512)) * (1.0f / 512.0f);
  const int plx = lane ^ 63;
  const int pl0 = (int)(__brev((unsigned)((64 - rev) & 63)) >> 26);
  const int h3 = lane >> 3;
  const int rev3h = ((h3 & 1) << 2) | (h3 & 2) | ((h3 >> 2) & 1);
  const int wbase = 9 * (rev3h << 3) + (lane & 7);
  const int caOff[8] = {9, 45, 27, 63, 0, 36, 18, 54};

  float Wr[6], Wi[6];
#pragma unroll
  for (int s = 0; s < 6; ++s) {
    const int h = 32 >> s;
    float th = (float)(lane & (h - 1)) * (3.14159265358979323846f / (float)h);
    float sn, cs;
    sincosf(th, &sn, &cs);
    Wr[s] = cs; Wi[s] = -sn;
  }
  float twFr[8], twFi[8];
  twFr[0] = 1.0f; twFi[0] = 0.0f;
#pragma unroll
  for (int b = 1; b < 8; ++b) {
    float th = (float)(lane * b) * 0.01227184630308513f;
    float sn, cs;
    sincosf(th, &sn, &cs);
    twFr[b] = cs; twFi[b] = -sn;
  }

  // ---- coalesced load: float4 (n, d0..d0+3) -> stage[seq][n] ----
  {
    const float4* x4 = (const float4*)x;
    float4 va = x4[base4 + tid * 32];
    float4 vb = x4[base4 + (tid + 256) * 32];
    stage[tid]        = va.x; stage[512 + tid]        = va.y;
    stage[1024 + tid] = va.z; stage[1536 + tid]       = va.w;
    stage[tid + 256]        = vb.x; stage[512 + tid + 256]  = vb.y;
    stage[1024 + tid + 256] = vb.z; stage[1536 + tid + 256] = vb.w;
  }
  __syncthreads();

  float Xr[8], Xi[8];
#pragma unroll
  for (int a = 0; a < 8; ++a) {
    float xv = stage[wv * 512 + a * 64 + lane];
    Xr[a] = xv; Xi[a] = 0.0f;
  }
  fft512_fwd(Xr, Xi, twFr, twFi, Wr, Wi, lane);

  float U0r[8], U0i[8], U1r[8], U1i[8], lamW[8], lamF[8];
#pragma unroll
  for (int b = 0; b < 8; ++b) {
    U0r[b] = 0.0f; U0i[b] = 0.0f; U1r[b] = 0.0f; U1i[b] = 0.0f;
    lamW[b] = 0.0f; lamF[b] = 0.0f;
  }
  float om0 = 0.0f, om1 = 0.0f;

#pragma unroll 1
  for (int it = 0; it < 50; ++it) {
    mode_update(Xr, Xi, U1r, U1i, U0r, U0i, lamF, om0, fbase, pl0, plx);
    mode_update(Xr, Xi, U0r, U0i, U1r, U1i, lamF, om1, fbase, pl0, plx);

    float n0 = 0.0f, d0s = 0.0f, n1 = 0.0f, d1 = 0.0f;
#pragma unroll
    for (int b = 0; b < 8; ++b) {
      float f = fbase + (float)b * (1.0f / 512.0f);
      float p0 = U0r[b] * U0r[b] + U0i[b] * U0i[b];
      float p1 = U1r[b] * U1r[b] + U1i[b] * U1i[b];
      n0 = fmaf(f, p0, n0); d0s += p0;
      n1 = fmaf(f, p1, n1); d1 += p1;
    }
    n0 *= pm; d0s *= pm; n1 *= pm; d1 *= pm;
#pragma unroll
    for (int off = 32; off >= 1; off >>= 1) {
      n0 += __shfl_xor(n0, off, 64);
      d0s += __shfl_xor(d0s, off, 64);
      n1 += __shfl_xor(n1, off, 64);
      d1 += __shfl_xor(d1, off, 64);
    }
    om0 = n0 / (d0s + 1e-7f);
    om1 = n1 / (d1 + 1e-7f);

    if (it < 49) {   // last iteration's lambda is never consumed
      float Sr[8], Si[8];
#pragma unroll
      for (int b = 0; b < 8; ++b) { Sr[b] = U0r[b] + U1r[b]; Si[b] = U0i[b] + U1i[b]; }
      fft512_inv(Sr, Si, twFr, twFi, Wr, Wi, lane);
#pragma unroll
      for (int a = 0; a < 8; ++a) {
        float xv = stage[wv * 512 + a * 64 + lane];   // x from LDS (saves 8 VGPRs)
        lamW[a] = fmaf(0.001f, xv - Sr[a] * (1.0f / 512.0f), lamW[a]);
      }
#pragma unroll
      for (int a = 0; a < 8; ++a) lamLds[wbase + caOff[a]] = lamW[a];
      asm volatile("s_waitcnt lgkmcnt(0)" ::: "memory");
#pragma unroll
      for (int b = 0; b < 8; ++b) lamF[b] = lamLds[9 * lane + b];
    }
  }

  // ---- final modes: ifft -> stage[seq][n] -> coalesced float4 stores ----
  float4* o4 = (float4*)out;
  {
    float Sr[8], Si[8];
#pragma unroll
    for (int b = 0; b < 8; ++b) { Sr[b] = U0r[b]; Si[b] = U0i[b]; }
    fft512_inv(Sr, Si, twFr, twFi, Wr, Wi, lane);
    __syncthreads();   // everyone done reading x from stage
#pragma unroll
    for (int a = 0; a < 8; ++a)
      stage[wv * 512 + a * 64 + lane] = Sr[a] * (1.0f / 512.0f);
  }
  __syncthreads();
#pragma unroll
  for (int r = 0; r < 2; ++r) {
    const int n = tid + r * 256;
    float4 v;
    v.x = stage[n]; v.y = stage[512 + n]; v.z = stage[1024 + n]; v.w = stage[1536 + n];
    o4[FIELD / 4 + base4 + n * 32] = v;
  }
  __syncthreads();
  {
    float Sr[8], Si[8];
#pragma unroll
    for (int b = 0; b < 8; ++b) { Sr[b] = U1r[b]; Si[b] = U1i[b]; }
    fft512_inv(Sr, Si, twFr, twFi, Wr, Wi, lane);
#pragma unroll
    for (int a = 0; a < 8; ++a)
      stage[wv * 512 + a * 64 + lane] = Sr[a] * (1.0f / 512.0f);
  }
  __syncthreads();
#pragma unroll
  for (int r = 0; r < 2; ++r) {
    const int n = tid + r * 256;
    float4 v;
    v.x = stage[n]; v.y = stage[512 + n]; v.z = stage[1024 + n]; v.w = stage[1536 + n];
    o4[2 * FIELD / 4 + base4 + n * 32] = v;
  }

  if (lane == 0) {
    out[g] = om0;            // staged in trend region (zeroed later)
    out[NSEQ + g] = om1;
  }
}

__global__ __launch_bounds__(128) void order_kernel(float* __restrict__ out) {
  const int bb = blockIdx.x;
  const int dd = threadIdx.x;
  float o0 = out[bb * 128 + dd];
  float o1 = out[NSEQ + bb * 128 + dd];
#pragma unroll
  for (int off = 32; off >= 1; off >>= 1) {
    o0 += __shfl_down(o0, off);
    o1 += __shfl_down(o1, off);
  }
  __shared__ float s0[2], s1[2];
  const int wv = dd >> 6;
  if ((dd & 63) == 0) { s0[wv] = o0; s1[wv] = o1; }
  __syncthreads();
  if (dd == 0) {
    const float a = s0[0] + s0[1];
    const float c = s1[0] + s1[1];
    out[2 * NSEQ + bb] = (a > c) ? 1.0f : 0.0f;
  }
}

__global__ __launch_bounds__(256) void swap_kernel(float* __restrict__ out) {
  const int idx = blockIdx.x * 256 + threadIdx.x;
  const int bb = idx >> 16;
  const float flag = out[2 * NSEQ + bb];
  if (flag > 0.5f) {
    const float p = out[FIELD + idx];
    const float r = out[2 * FIELD + idx];
    out[FIELD + idx] = r;
    out[2 * FIELD + idx] = p;
  }
}

extern "C" void kernel_launch(void* const* d_in, const int* in_sizes, int n_in,
                              void* d_out, int out_size, void* d_ws, size_t ws_size,
                              hipStream_t stream) {
  (void)in_sizes; (void)n_in; (void)d_ws; (void)ws_size; (void)out_size;
  const float* x = (const float*)d_in[0];
  float* out = (float*)d_out;
  vmd_kernel<<<NSEQ / 4, 256, 0, stream>>>(x, out);
  order_kernel<<<32, 128, 0, stream>>>(out);
  swap_kernel<<<FIELD / 256, 256, 0, stream>>>(out);
  hipMemsetAsync(out, 0, (size_t)FIELD * sizeof(float), stream);
}

// Round 5
// 471.691 us; speedup vs baseline: 1.5164x; 1.2793x over previous
//
#include <hip/hip_runtime.h>
#include <math.h>

#define FIELD 2097152   // 32*512*128
#define NSEQ  4096      // 32*128 sequences

// ---------------------------------------------------------------------------
// 8-point FFT over a lane's 8 register slots (natural-order DFT).
// ---------------------------------------------------------------------------
__device__ __forceinline__ void fft8(float* re, float* im, const bool inv) {
  float y0r = re[0]+re[4], y0i = im[0]+im[4];
  float y1r = re[0]-re[4], y1i = im[0]-im[4];
  float y2r = re[2]+re[6], y2i = im[2]+im[6];
  float y3r = re[2]-re[6], y3i = im[2]-im[6];
  float y4r = re[1]+re[5], y4i = im[1]+im[5];
  float y5r = re[1]-re[5], y5i = im[1]-im[5];
  float y6r = re[3]+re[7], y6i = im[3]+im[7];
  float y7r = re[3]-re[7], y7i = im[3]-im[7];
  float t3r = inv ? -y3i : y3i,  t3i = inv ? y3r : -y3r;
  float t7r = inv ? -y7i : y7i,  t7i = inv ? y7r : -y7r;
  float z0r = y0r+y2r, z0i = y0i+y2i;
  float z2r = y0r-y2r, z2i = y0i-y2i;
  float z1r = y1r+t3r, z1i = y1i+t3i;
  float z3r = y1r-t3r, z3i = y1i-t3i;
  float z4r = y4r+y6r, z4i = y4i+y6i;
  float z6r = y4r-y6r, z6i = y4i-y6i;
  float z5r = y5r+t7r, z5i = y5i+t7i;
  float z7r = y5r-t7r, z7i = y5i-t7i;
  const float R = 0.70710678118654752440f;
  const float s = inv ? R : -R;
  float a5r = R*z5r - s*z5i, a5i = R*z5i + s*z5r;
  float a6r = inv ? -z6i : z6i, a6i = inv ? z6r : -z6r;
  float a7r = -R*z7r - s*z7i, a7i = -R*z7i + s*z7r;
  re[0] = z0r+z4r; im[0] = z0i+z4i;
  re[4] = z0r-z4r; im[4] = z0i-z4i;
  re[1] = z1r+a5r; im[1] = z1i+a5i;
  re[5] = z1r-a5r; im[5] = z1i-a5i;
  re[2] = z2r+a6r; im[2] = z2i+a6i;
  re[6] = z2r-a6r; im[6] = z2i-a6i;
  re[3] = z3r+a7r; im[3] = z3i+a7i;
  re[7] = z3r-a7r; im[7] = z3i-a7i;
}

// 64-point FFT across lanes (radix-2, 6 stages of shfl_xor).
__device__ __forceinline__ void fft64_fwd(float* vr, float* vi,
                                          const float* Wr, const float* Wi,
                                          int lane) {
#pragma unroll
  for (int s = 0; s < 6; ++s) {
    const int h = 32 >> s;
    const bool hi = (lane & h) != 0;
    const float sg = hi ? -1.0f : 1.0f;
#pragma unroll
    for (int b = 0; b < 8; ++b) {
      float pr = __shfl_xor(vr[b], h, 64);
      float pi = __shfl_xor(vi[b], h, 64);
      float tr = fmaf(sg, vr[b], pr);
      float ti = fmaf(sg, vi[b], pi);
      float mr = tr * Wr[s] - ti * Wi[s];
      float mi = tr * Wi[s] + ti * Wr[s];
      vr[b] = hi ? mr : tr;
      vi[b] = hi ? mi : ti;
    }
  }
}

__device__ __forceinline__ void fft64_inv(float* vr, float* vi,
                                          const float* Wr, const float* Wi,
                                          int lane) {
#pragma unroll
  for (int s = 5; s >= 0; --s) {
    const int h = 32 >> s;
    const bool hi = (lane & h) != 0;
    const float sg = hi ? -1.0f : 1.0f;
#pragma unroll
    for (int b = 0; b < 8; ++b) {
      float pr = __shfl_xor(vr[b], h, 64);
      float pi = __shfl_xor(vi[b], h, 64);
      float qr = hi ? vr[b] : pr;
      float qi = hi ? vi[b] : pi;
      float rr = hi ? pr : vr[b];
      float ri = hi ? pi : vi[b];
      float tr = fmaf(Wr[s], qr,  Wi[s] * qi);
      float ti = fmaf(Wr[s], qi, -(Wi[s] * qr));
      vr[b] = fmaf(sg, tr, rr);
      vi[b] = fmaf(sg, ti, ri);
    }
  }
}

__device__ __forceinline__ void fft512_fwd(float* vr, float* vi,
                                           const float* twFr, const float* twFi,
                                           const float* Wr, const float* Wi,
                                           int lane) {
  fft8(vr, vi, false);
#pragma unroll
  for (int b = 1; b < 8; ++b) {
    float ar = vr[b], ai = vi[b];
    vr[b] = ar * twFr[b] - ai * twFi[b];
    vi[b] = ar * twFi[b] + ai * twFr[b];
  }
  fft64_fwd(vr, vi, Wr, Wi, lane);
}

__device__ __forceinline__ void fft512_inv(float* vr, float* vi,
                                           const float* twFr, const float* twFi,
                                           const float* Wr, const float* Wi,
                                           int lane) {
  fft64_inv(vr, vi, Wr, Wi, lane);
#pragma unroll
  for (int b = 1; b < 8; ++b) {
    float ar = vr[b], ai = vi[b];
    vr[b] = ar * twFr[b] + ai * twFi[b];
    vi[b] = ai * twFr[b] - ar * twFi[b];
  }
  fft8(vr, vi, true);
}

__device__ __forceinline__ void mode_update(const float* Xr, const float* Xi,
                                            const float* Vr, const float* Vi,
                                            float* Ur, float* Ui,
                                            const float* lamF, float om,
                                            float fbase, int pl0, int plx) {
  float Tr[8], Ti[8];
#pragma unroll
  for (int b = 0; b < 8; ++b) {
    float fb = fbase + (float)b * (1.0f / 512.0f);
    float df = fb - om;
    float den = __builtin_amdgcn_rcpf(fmaf(1600.0f * df, df, 1.0f));
    Tr[b] = (Xr[b] - Vr[b] + 0.5f * lamF[b]) * den;
    Ti[b] = (Xi[b] - Vi[b]) * den;
  }
#pragma unroll
  for (int b = 0; b < 8; ++b) {
    const int pb = (8 - b) & 7;
    const int pl = (b == 0) ? pl0 : plx;
    float sr = __shfl(Tr[pb], pl, 64);
    float si = __shfl(Ti[pb], pl, 64);
    Ur[b] = 0.5f * (Tr[b] + sr);
    Ui[b] = 0.5f * (Ti[b] - si);
  }
}

// One wave per (b,d) sequence; 4 waves/block covering 4 consecutive d.
// amdgpu_waves_per_eu(3,3): pin occupancy to exactly 3 waves/EU so the
// allocator budget is ~168 VGPRs — round 4 showed __launch_bounds__(256,3)
// (min-only) lets LLVM target 6 waves/EU at 84 VGPRs and spill ~8 floats/iter
// to scratch (320 MB fetch + 410 MB write of pure spill traffic).
// Lambda accumulator lives in LDS (never in long-lived registers).
__global__ __attribute__((amdgpu_flat_work_group_size(256, 256),
                          amdgpu_waves_per_eu(3, 3)))
void vmd_kernel(const float* __restrict__ x, float* __restrict__ out) {
  __shared__ float stage[4 * 512];    // [seq][n]; x resident during loop, reused for out
  __shared__ float ldsLam[4 * 576];   // stride-9 permuted lambda accumulator per wave

  const int tid = threadIdx.x;
  const int wv = tid >> 6;
  const int lane = tid & 63;
  // blockIdx%8 -> XCD (heuristic): consecutive w on same XCD.
  const int w = (blockIdx.x >> 3) + ((blockIdx.x & 7) << 7);   // 0..1023
  const int g = 4 * w + wv;           // sequence id 0..4095
  const int bb = w >> 5;              // batch 0..31
  const int d0 = (4 * w) & 127;       // 4-aligned d of this block
  const int base4 = bb * 16384 + (d0 >> 2);   // float4 index of (bb,0,d0)
  float* lamLds = ldsLam + wv * 576;

  const int rev = (int)(__brev((unsigned)lane) >> 26);   // rev6(lane)
  const int m0 = rev << 3;
  const bool pos = (lane & 1) == 0;                       // m < 256
  const float pm = pos ? 1.0f : 0.0f;
  const float fbase = (float)(m0 - (pos ? 0 : 512)) * (1.0f / 512.0f);
  const int plx = lane ^ 63;
  const int pl0 = (int)(__brev((unsigned)((64 - rev) & 63)) >> 26);
  const int h3 = lane >> 3;
  const int rev3h = ((h3 & 1) << 2) | (h3 & 2) | ((h3 >> 2) & 1);
  const int wbase = 9 * (rev3h << 3) + (lane & 7);
  const int caOff[8] = {9, 45, 27, 63, 0, 36, 18, 54};

  float Wr[6], Wi[6];
#pragma unroll
  for (int s = 0; s < 6; ++s) {
    const int h = 32 >> s;
    float th = (float)(lane & (h - 1)) * (3.14159265358979323846f / (float)h);
    float sn, cs;
    sincosf(th, &sn, &cs);
    Wr[s] = cs; Wi[s] = -sn;
  }
  float twFr[8], twFi[8];
  twFr[0] = 1.0f; twFi[0] = 0.0f;
#pragma unroll
  for (int b = 1; b < 8; ++b) {
    float th = (float)(lane * b) * 0.01227184630308513f;
    float sn, cs;
    sincosf(th, &sn, &cs);
    twFr[b] = cs; twFi[b] = -sn;
  }

  // ---- load x: float4 (n, d0..d0+3) -> stage[seq][n]; zero lambda buffer ----
  {
    const float4* x4 = (const float4*)x;
    float4 va = x4[base4 + tid * 32];
    float4 vb = x4[base4 + (tid + 256) * 32];
    stage[tid]        = va.x; stage[512 + tid]        = va.y;
    stage[1024 + tid] = va.z; stage[1536 + tid]       = va.w;
    stage[tid + 256]        = vb.x; stage[512 + tid + 256]  = vb.y;
    stage[1024 + tid + 256] = vb.z; stage[1536 + tid + 256] = vb.w;
#pragma unroll
    for (int j = 0; j < 9; ++j) ldsLam[tid * 9 + j] = 0.0f;   // harness poisons ws
  }
  __syncthreads();

  float Xr[8], Xi[8];
#pragma unroll
  for (int a = 0; a < 8; ++a) {
    float xv = stage[wv * 512 + a * 64 + lane];
    Xr[a] = xv; Xi[a] = 0.0f;
  }
  fft512_fwd(Xr, Xi, twFr, twFi, Wr, Wi, lane);

  float U0r[8], U0i[8], U1r[8], U1i[8];
#pragma unroll
  for (int b = 0; b < 8; ++b) {
    U0r[b] = 0.0f; U0i[b] = 0.0f; U1r[b] = 0.0f; U1i[b] = 0.0f;
  }
  float om0 = 0.0f, om1 = 0.0f;

#pragma unroll 1
  for (int it = 0; it < 50; ++it) {
    // lamF: short-lived registers, dead before the ifft (pressure peak)
    float lamF[8];
#pragma unroll
    for (int b = 0; b < 8; ++b) lamF[b] = lamLds[9 * lane + b];

    mode_update(Xr, Xi, U1r, U1i, U0r, U0i, lamF, om0, fbase, pl0, plx);
    mode_update(Xr, Xi, U0r, U0i, U1r, U1i, lamF, om1, fbase, pl0, plx);

    float n0 = 0.0f, d0s = 0.0f, n1 = 0.0f, d1 = 0.0f;
#pragma unroll
    for (int b = 0; b < 8; ++b) {
      float f = fbase + (float)b * (1.0f / 512.0f);
      float p0 = U0r[b] * U0r[b] + U0i[b] * U0i[b];
      float p1 = U1r[b] * U1r[b] + U1i[b] * U1i[b];
      n0 = fmaf(f, p0, n0); d0s += p0;
      n1 = fmaf(f, p1, n1); d1 += p1;
    }
    n0 *= pm; d0s *= pm; n1 *= pm; d1 *= pm;
#pragma unroll
    for (int off = 32; off >= 1; off >>= 1) {
      n0 += __shfl_xor(n0, off, 64);
      d0s += __shfl_xor(d0s, off, 64);
      n1 += __shfl_xor(n1, off, 64);
      d1 += __shfl_xor(d1, off, 64);
    }
    om0 = n0 / (d0s + 1e-7f);
    om1 = n1 / (d1 + 1e-7f);

    if (it < 49) {   // last iteration's lambda is never consumed
      float Sr[8], Si[8];
#pragma unroll
      for (int b = 0; b < 8; ++b) { Sr[b] = U0r[b] + U1r[b]; Si[b] = U0i[b] + U1i[b]; }
      fft512_inv(Sr, Si, twFr, twFi, Wr, Wi, lane);
      // lambda accumulate: LDS read-modify-write (stride-9 permuted layout)
#pragma unroll
      for (int a = 0; a < 8; ++a) {
        float xv = stage[wv * 512 + a * 64 + lane];
        float cur = lamLds[wbase + caOff[a]];
        lamLds[wbase + caOff[a]] =
            fmaf(0.001f, xv - Sr[a] * (1.0f / 512.0f), cur);
      }
      asm volatile("s_waitcnt lgkmcnt(0)" ::: "memory");
    }
  }

  // ---- final modes: ifft -> stage[seq][n] -> float4 stores ----
  float4* o4 = (float4*)out;
  {
    float Sr[8], Si[8];
#pragma unroll
    for (int b = 0; b < 8; ++b) { Sr[b] = U0r[b]; Si[b] = U0i[b]; }
    fft512_inv(Sr, Si, twFr, twFi, Wr, Wi, lane);
    __syncthreads();   // everyone done reading x from stage
#pragma unroll
    for (int a = 0; a < 8; ++a)
      stage[wv * 512 + a * 64 + lane] = Sr[a] * (1.0f / 512.0f);
  }
  __syncthreads();
#pragma unroll
  for (int r = 0; r < 2; ++r) {
    const int n = tid + r * 256;
    float4 v;
    v.x = stage[n]; v.y = stage[512 + n]; v.z = stage[1024 + n]; v.w = stage[1536 + n];
    o4[FIELD / 4 + base4 + n * 32] = v;
  }
  __syncthreads();
  {
    float Sr[8], Si[8];
#pragma unroll
    for (int b = 0; b < 8; ++b) { Sr[b] = U1r[b]; Si[b] = U1i[b]; }
    fft512_inv(Sr, Si, twFr, twFi, Wr, Wi, lane);
#pragma unroll
    for (int a = 0; a < 8; ++a)
      stage[wv * 512 + a * 64 + lane] = Sr[a] * (1.0f / 512.0f);
  }
  __syncthreads();
#pragma unroll
  for (int r = 0; r < 2; ++r) {
    const int n = tid + r * 256;
    float4 v;
    v.x = stage[n]; v.y = stage[512 + n]; v.z = stage[1024 + n]; v.w = stage[1536 + n];
    o4[2 * FIELD / 4 + base4 + n * 32] = v;
  }

  if (lane == 0) {
    out[g] = om0;            // staged in trend region (zeroed later)
    out[NSEQ + g] = om1;
  }
}

__global__ __launch_bounds__(128) void order_kernel(float* __restrict__ out) {
  const int bb = blockIdx.x;
  const int dd = threadIdx.x;
  float o0 = out[bb * 128 + dd];
  float o1 = out[NSEQ + bb * 128 + dd];
#pragma unroll
  for (int off = 32; off >= 1; off >>= 1) {
    o0 += __shfl_down(o0, off);
    o1 += __shfl_down(o1, off);
  }
  __shared__ float s0[2], s1[2];
  const int wv = dd >> 6;
  if ((dd & 63) == 0) { s0[wv] = o0; s1[wv] = o1; }
  __syncthreads();
  if (dd == 0) {
    const float a = s0[0] + s0[1];
    const float c = s1[0] + s1[1];
    out[2 * NSEQ + bb] = (a > c) ? 1.0f : 0.0f;
  }
}

__global__ __launch_bounds__(256) void swap_kernel(float* __restrict__ out) {
  const int idx = blockIdx.x * 256 + threadIdx.x;
  const int bb = idx >> 16;
  const float flag = out[2 * NSEQ + bb];
  if (flag > 0.5f) {
    const float p = out[FIELD + idx];
    const float r = out[2 * FIELD + idx];
    out[FIELD + idx] = r;
    out[2 * FIELD + idx] = p;
  }
}

extern "C" void kernel_launch(void* const* d_in, const int* in_sizes, int n_in,
                              void* d_out, int out_size, void* d_ws, size_t ws_size,
                              hipStream_t stream) {
  (void)in_sizes; (void)n_in; (void)d_ws; (void)ws_size; (void)out_size;
  const float* x = (const float*)d_in[0];
  float* out = (float*)d_out;
  vmd_kernel<<<NSEQ / 4, 256, 0, stream>>>(x, out);
  order_kernel<<<32, 128, 0, stream>>>(out);
  swap_kernel<<<FIELD / 256, 256, 0, stream>>>(out);
  hipMemsetAsync(out, 0, (size_t)FIELD * sizeof(float), stream);
}

// Round 6
// 466.450 us; speedup vs baseline: 1.5334x; 1.0112x over previous
//
#include <hip/hip_runtime.h>
#include <math.h>

#define FIELD 2097152   // 32*512*128
#define NSEQ  4096      // 32*128 sequences

// ---------------------------------------------------------------------------
// 8-point FFT over a lane's 8 register slots (natural-order DFT).
// ---------------------------------------------------------------------------
__device__ __forceinline__ void fft8(float* re, float* im, const bool inv) {
  float y0r = re[0]+re[4], y0i = im[0]+im[4];
  float y1r = re[0]-re[4], y1i = im[0]-im[4];
  float y2r = re[2]+re[6], y2i = im[2]+im[6];
  float y3r = re[2]-re[6], y3i = im[2]-im[6];
  float y4r = re[1]+re[5], y4i = im[1]+im[5];
  float y5r = re[1]-re[5], y5i = im[1]-im[5];
  float y6r = re[3]+re[7], y6i = im[3]+im[7];
  float y7r = re[3]-re[7], y7i = im[3]-im[7];
  float t3r = inv ? -y3i : y3i,  t3i = inv ? y3r : -y3r;
  float t7r = inv ? -y7i : y7i,  t7i = inv ? y7r : -y7r;
  float z0r = y0r+y2r, z0i = y0i+y2i;
  float z2r = y0r-y2r, z2i = y0i-y2i;
  float z1r = y1r+t3r, z1i = y1i+t3i;
  float z3r = y1r-t3r, z3i = y1i-t3i;
  float z4r = y4r+y6r, z4i = y4i+y6i;
  float z6r = y4r-y6r, z6i = y4i-y6i;
  float z5r = y5r+t7r, z5i = y5i+t7i;
  float z7r = y5r-t7r, z7i = y5i-t7i;
  const float R = 0.70710678118654752440f;
  const float s = inv ? R : -R;
  float a5r = R*z5r - s*z5i, a5i = R*z5i + s*z5r;
  float a6r = inv ? -z6i : z6i, a6i = inv ? z6r : -z6r;
  float a7r = -R*z7r - s*z7i, a7i = -R*z7i + s*z7r;
  re[0] = z0r+z4r; im[0] = z0i+z4i;
  re[4] = z0r-z4r; im[4] = z0i-z4i;
  re[1] = z1r+a5r; im[1] = z1i+a5i;
  re[5] = z1r-a5r; im[5] = z1i-a5i;
  re[2] = z2r+a6r; im[2] = z2i+a6i;
  re[6] = z2r-a6r; im[6] = z2i-a6i;
  re[3] = z3r+a7r; im[3] = z3i+a7i;
  re[7] = z3r-a7r; im[7] = z3i-a7i;
}

// 64-point FFT across lanes (radix-2, 6 stages of shfl_xor).
__device__ __forceinline__ void fft64_fwd(float* vr, float* vi,
                                          const float* Wr, const float* Wi,
                                          int lane) {
#pragma unroll
  for (int s = 0; s < 6; ++s) {
    const int h = 32 >> s;
    const bool hi = (lane & h) != 0;
    const float sg = hi ? -1.0f : 1.0f;
#pragma unroll
    for (int b = 0; b < 8; ++b) {
      float pr = __shfl_xor(vr[b], h, 64);
      float pi = __shfl_xor(vi[b], h, 64);
      float tr = fmaf(sg, vr[b], pr);
      float ti = fmaf(sg, vi[b], pi);
      float mr = tr * Wr[s] - ti * Wi[s];
      float mi = tr * Wi[s] + ti * Wr[s];
      vr[b] = hi ? mr : tr;
      vi[b] = hi ? mi : ti;
    }
  }
}

__device__ __forceinline__ void fft64_inv(float* vr, float* vi,
                                          const float* Wr, const float* Wi,
                                          int lane) {
#pragma unroll
  for (int s = 5; s >= 0; --s) {
    const int h = 32 >> s;
    const bool hi = (lane & h) != 0;
    const float sg = hi ? -1.0f : 1.0f;
#pragma unroll
    for (int b = 0; b < 8; ++b) {
      float pr = __shfl_xor(vr[b], h, 64);
      float pi = __shfl_xor(vi[b], h, 64);
      float qr = hi ? vr[b] : pr;
      float qi = hi ? vi[b] : pi;
      float rr = hi ? pr : vr[b];
      float ri = hi ? pi : vi[b];
      float tr = fmaf(Wr[s], qr,  Wi[s] * qi);
      float ti = fmaf(Wr[s], qi, -(Wi[s] * qr));
      vr[b] = fmaf(sg, tr, rr);
      vi[b] = fmaf(sg, ti, ri);
    }
  }
}

__device__ __forceinline__ void fft512_fwd(float* vr, float* vi,
                                           const float* twFr, const float* twFi,
                                           const float* Wr, const float* Wi,
                                           int lane) {
  fft8(vr, vi, false);
#pragma unroll
  for (int b = 1; b < 8; ++b) {
    float ar = vr[b], ai = vi[b];
    vr[b] = ar * twFr[b] - ai * twFi[b];
    vi[b] = ar * twFi[b] + ai * twFr[b];
  }
  fft64_fwd(vr, vi, Wr, Wi, lane);
}

__device__ __forceinline__ void fft512_inv(float* vr, float* vi,
                                           const float* twFr, const float* twFi,
                                           const float* Wr, const float* Wi,
                                           int lane) {
  fft64_inv(vr, vi, Wr, Wi, lane);
#pragma unroll
  for (int b = 1; b < 8; ++b) {
    float ar = vr[b], ai = vi[b];
    vr[b] = ar * twFr[b] + ai * twFi[b];
    vi[b] = ai * twFr[b] - ar * twFi[b];
  }
  fft8(vr, vi, true);
}

__device__ __forceinline__ void mode_update(const float* Xr, const float* Xi,
                                            const float* Vr, const float* Vi,
                                            float* Ur, float* Ui,
                                            const float* lamF, float om,
                                            float fbase, int pl0, int plx) {
  float Tr[8], Ti[8];
#pragma unroll
  for (int b = 0; b < 8; ++b) {
    float fb = fbase + (float)b * (1.0f / 512.0f);
    float df = fb - om;
    float den = __builtin_amdgcn_rcpf(fmaf(1600.0f * df, df, 1.0f));
    Tr[b] = (Xr[b] - Vr[b] + 0.5f * lamF[b]) * den;
    Ti[b] = (Xi[b] - Vi[b]) * den;
  }
#pragma unroll
  for (int b = 0; b < 8; ++b) {
    const int pb = (8 - b) & 7;
    const int pl = (b == 0) ? pl0 : plx;
    float sr = __shfl(Tr[pb], pl, 64);
    float si = __shfl(Ti[pb], pl, 64);
    Ur[b] = 0.5f * (Tr[b] + sr);
    Ui[b] = 0.5f * (Ti[b] - si);
  }
}

// One wave per (b,d) sequence; 4 waves/block covering 4 consecutive d.
// waves_per_eu(4,4): 16 waves/CU = exactly 4 blocks/CU -> all 1024 blocks
// co-resident in ONE pass (round 5's (3,3) pin left a 256-block tail pass at
// 12.5% occupancy; measured avg occupancy 26% vs 37.5% pinned).
// VGPR budget 128 vs measured pressure ~80-90 (lambda lives in LDS), no spill.
__global__ __attribute__((amdgpu_flat_work_group_size(256, 256),
                          amdgpu_waves_per_eu(4, 4)))
void vmd_kernel(const float* __restrict__ x, float* __restrict__ out) {
  __shared__ float stage[4 * 512];    // [seq][n] transpose buffer (in & out)
  __shared__ float ldsLam[4 * 576];   // stride-9 permuted lambda accumulator per wave

  const int tid = threadIdx.x;
  const int wv = tid >> 6;
  const int lane = tid & 63;
  // blockIdx%8 -> XCD (heuristic): consecutive w on same XCD.
  const int w = (blockIdx.x >> 3) + ((blockIdx.x & 7) << 7);   // 0..1023
  const int g = 4 * w + wv;           // sequence id 0..4095
  const int bb = w >> 5;              // batch 0..31
  const int d0 = (4 * w) & 127;       // 4-aligned d of this block
  const int base4 = bb * 16384 + (d0 >> 2);   // float4 index of (bb,0,d0)
  float* lamLds = ldsLam + wv * 576;

  const int rev = (int)(__brev((unsigned)lane) >> 26);   // rev6(lane)
  const int m0 = rev << 3;
  const bool pos = (lane & 1) == 0;                       // m < 256
  const float pm = pos ? 1.0f : 0.0f;
  const float fbase = (float)(m0 - (pos ? 0 : 512)) * (1.0f / 512.0f);
  const int plx = lane ^ 63;
  const int pl0 = (int)(__brev((unsigned)((64 - rev) & 63)) >> 26);
  const int h3 = lane >> 3;
  const int rev3h = ((h3 & 1) << 2) | (h3 & 2) | ((h3 >> 2) & 1);
  const int wbase = 9 * (rev3h << 3) + (lane & 7);
  const int caOff[8] = {9, 45, 27, 63, 0, 36, 18, 54};

  float Wr[6], Wi[6];
#pragma unroll
  for (int s = 0; s < 6; ++s) {
    const int h = 32 >> s;
    float th = (float)(lane & (h - 1)) * (3.14159265358979323846f / (float)h);
    float sn, cs;
    sincosf(th, &sn, &cs);
    Wr[s] = cs; Wi[s] = -sn;
  }
  float twFr[8], twFi[8];
  twFr[0] = 1.0f; twFi[0] = 0.0f;
#pragma unroll
  for (int b = 1; b < 8; ++b) {
    float th = (float)(lane * b) * 0.01227184630308513f;
    float sn, cs;
    sincosf(th, &sn, &cs);
    twFr[b] = cs; twFi[b] = -sn;
  }

  // ---- load x: float4 (n, d0..d0+3) -> stage[seq][n]; zero lambda buffer ----
  {
    const float4* x4 = (const float4*)x;
    float4 va = x4[base4 + tid * 32];
    float4 vb = x4[base4 + (tid + 256) * 32];
    stage[tid]        = va.x; stage[512 + tid]        = va.y;
    stage[1024 + tid] = va.z; stage[1536 + tid]       = va.w;
    stage[tid + 256]        = vb.x; stage[512 + tid + 256]  = vb.y;
    stage[1024 + tid + 256] = vb.z; stage[1536 + tid + 256] = vb.w;
#pragma unroll
    for (int j = 0; j < 9; ++j) ldsLam[tid * 9 + j] = 0.0f;   // harness poisons ws
  }
  __syncthreads();

  float xT[8], Xr[8], Xi[8];
#pragma unroll
  for (int a = 0; a < 8; ++a) {
    float xv = stage[wv * 512 + a * 64 + lane];
    xT[a] = xv; Xr[a] = xv; Xi[a] = 0.0f;
  }
  fft512_fwd(Xr, Xi, twFr, twFi, Wr, Wi, lane);

  float U0r[8], U0i[8], U1r[8], U1i[8];
#pragma unroll
  for (int b = 0; b < 8; ++b) {
    U0r[b] = 0.0f; U0i[b] = 0.0f; U1r[b] = 0.0f; U1i[b] = 0.0f;
  }
  float om0 = 0.0f, om1 = 0.0f;

#pragma unroll 1
  for (int it = 0; it < 50; ++it) {
    // lamF: short-lived registers, dead before the ifft (pressure peak)
    float lamF[8];
#pragma unroll
    for (int b = 0; b < 8; ++b) lamF[b] = lamLds[9 * lane + b];

    mode_update(Xr, Xi, U1r, U1i, U0r, U0i, lamF, om0, fbase, pl0, plx);
    mode_update(Xr, Xi, U0r, U0i, U1r, U1i, lamF, om1, fbase, pl0, plx);

    float n0 = 0.0f, d0s = 0.0f, n1 = 0.0f, d1 = 0.0f;
#pragma unroll
    for (int b = 0; b < 8; ++b) {
      float f = fbase + (float)b * (1.0f / 512.0f);
      float p0 = U0r[b] * U0r[b] + U0i[b] * U0i[b];
      float p1 = U1r[b] * U1r[b] + U1i[b] * U1i[b];
      n0 = fmaf(f, p0, n0); d0s += p0;
      n1 = fmaf(f, p1, n1); d1 += p1;
    }
    n0 *= pm; d0s *= pm; n1 *= pm; d1 *= pm;
#pragma unroll
    for (int off = 32; off >= 1; off >>= 1) {
      n0 += __shfl_xor(n0, off, 64);
      d0s += __shfl_xor(d0s, off, 64);
      n1 += __shfl_xor(n1, off, 64);
      d1 += __shfl_xor(d1, off, 64);
    }
    om0 = n0 / (d0s + 1e-7f);
    om1 = n1 / (d1 + 1e-7f);

    if (it < 49) {   // last iteration's lambda is never consumed
      float Sr[8], Si[8];
#pragma unroll
      for (int b = 0; b < 8; ++b) { Sr[b] = U0r[b] + U1r[b]; Si[b] = U0i[b] + U1i[b]; }
      fft512_inv(Sr, Si, twFr, twFi, Wr, Wi, lane);
      // lambda accumulate: LDS read-modify-write (stride-9 permuted layout)
#pragma unroll
      for (int a = 0; a < 8; ++a) {
        float cur = lamLds[wbase + caOff[a]];
        lamLds[wbase + caOff[a]] =
            fmaf(0.001f, xT[a] - Sr[a] * (1.0f / 512.0f), cur);
      }
      asm volatile("s_waitcnt lgkmcnt(0)" ::: "memory");
    }
  }

  // ---- final modes: ifft -> stage[seq][n] -> float4 stores ----
  float4* o4 = (float4*)out;
  {
    float Sr[8], Si[8];
#pragma unroll
    for (int b = 0; b < 8; ++b) { Sr[b] = U0r[b]; Si[b] = U0i[b]; }
    fft512_inv(Sr, Si, twFr, twFi, Wr, Wi, lane);
    __syncthreads();   // stage free for reuse once all waves pass here
#pragma unroll
    for (int a = 0; a < 8; ++a)
      stage[wv * 512 + a * 64 + lane] = Sr[a] * (1.0f / 512.0f);
  }
  __syncthreads();
#pragma unroll
  for (int r = 0; r < 2; ++r) {
    const int n = tid + r * 256;
    float4 v;
    v.x = stage[n]; v.y = stage[512 + n]; v.z = stage[1024 + n]; v.w = stage[1536 + n];
    o4[FIELD / 4 + base4 + n * 32] = v;
  }
  __syncthreads();
  {
    float Sr[8], Si[8];
#pragma unroll
    for (int b = 0; b < 8; ++b) { Sr[b] = U1r[b]; Si[b] = U1i[b]; }
    fft512_inv(Sr, Si, twFr, twFi, Wr, Wi, lane);
#pragma unroll
    for (int a = 0; a < 8; ++a)
      stage[wv * 512 + a * 64 + lane] = Sr[a] * (1.0f / 512.0f);
  }
  __syncthreads();
#pragma unroll
  for (int r = 0; r < 2; ++r) {
    const int n = tid + r * 256;
    float4 v;
    v.x = stage[n]; v.y = stage[512 + n]; v.z = stage[1024 + n]; v.w = stage[1536 + n];
    o4[2 * FIELD / 4 + base4 + n * 32] = v;
  }

  if (lane == 0) {
    out[g] = om0;            // staged in trend region (zeroed later)
    out[NSEQ + g] = om1;
  }
}

__global__ __launch_bounds__(128) void order_kernel(float* __restrict__ out) {
  const int bb = blockIdx.x;
  const int dd = threadIdx.x;
  float o0 = out[bb * 128 + dd];
  float o1 = out[NSEQ + bb * 128 + dd];
#pragma unroll
  for (int off = 32; off >= 1; off >>= 1) {
    o0 += __shfl_down(o0, off);
    o1 += __shfl_down(o1, off);
  }
  __shared__ float s0[2], s1[2];
  const int wv = dd >> 6;
  if ((dd & 63) == 0) { s0[wv] = o0; s1[wv] = o1; }
  __syncthreads();
  if (dd == 0) {
    const float a = s0[0] + s0[1];
    const float c = s1[0] + s1[1];
    out[2 * NSEQ + bb] = (a > c) ? 1.0f : 0.0f;
  }
}

__global__ __launch_bounds__(256) void swap_kernel(float* __restrict__ out) {
  const int idx = blockIdx.x * 256 + threadIdx.x;
  const int bb = idx >> 16;
  const float flag = out[2 * NSEQ + bb];
  if (flag > 0.5f) {
    const float p = out[FIELD + idx];
    const float r = out[2 * FIELD + idx];
    out[FIELD + idx] = r;
    out[2 * FIELD + idx] = p;
  }
}

extern "C" void kernel_launch(void* const* d_in, const int* in_sizes, int n_in,
                              void* d_out, int out_size, void* d_ws, size_t ws_size,
                              hipStream_t stream) {
  (void)in_sizes; (void)n_in; (void)d_ws; (void)ws_size; (void)out_size;
  const float* x = (const float*)d_in[0];
  float* out = (float*)d_out;
  vmd_kernel<<<NSEQ / 4, 256, 0, stream>>>(x, out);
  order_kernel<<<32, 128, 0, stream>>>(out);
  swap_kernel<<<FIELD / 256, 256, 0, stream>>>(out);
  hipMemsetAsync(out, 0, (size_t)FIELD * sizeof(float), stream);
}

// Round 7
// 353.264 us; speedup vs baseline: 2.0248x; 1.3204x over previous
//
#include <hip/hip_runtime.h>
#include <math.h>

#define FIELD 2097152   // 32*512*128
#define NSEQ  4096      // 32*128 sequences

// ---------------------------------------------------------------------------
// DFT4 over the lane's 4 register slots.
// ---------------------------------------------------------------------------
__device__ __forceinline__ void fft4_fwd(float* re, float* im) {
  float t0r = re[0]+re[2], t0i = im[0]+im[2];
  float t1r = re[0]-re[2], t1i = im[0]-im[2];
  float t2r = re[1]+re[3], t2i = im[1]+im[3];
  float t3r = re[1]-re[3], t3i = im[1]-im[3];
  re[0] = t0r+t2r; im[0] = t0i+t2i;
  re[2] = t0r-t2r; im[2] = t0i-t2i;
  re[1] = t1r+t3i; im[1] = t1i-t3r;   // y1 = t1 - i t3
  re[3] = t1r-t3i; im[3] = t1i+t3r;   // y3 = t1 + i t3
}
__device__ __forceinline__ void fft4_inv(float* re, float* im) {
  float t0r = re[0]+re[2], t0i = im[0]+im[2];
  float t1r = re[0]-re[2], t1i = im[0]-im[2];
  float t2r = re[1]+re[3], t2i = im[1]+im[3];
  float t3r = re[1]-re[3], t3i = im[1]-im[3];
  re[0] = t0r+t2r; im[0] = t0i+t2i;
  re[2] = t0r-t2r; im[2] = t0i-t2i;
  re[1] = t1r-t3i; im[1] = t1i+t3r;   // z1 = t1 + i t3
  re[3] = t1r+t3i; im[3] = t1i-t3r;   // z3 = t1 - i t3
}

// 256-point FFT: time n = 64a+lane (slot a) <-> freq k = 4*rev6(lane)+b.
// twF[b-1] = e^{-2pi i lane b/256}; W[s] = e^{-i pi (lane&(h-1))/h}, h=32>>s.
__device__ __forceinline__ void fft256_fwd(float* vr, float* vi,
                                           const float* twFr, const float* twFi,
                                           const float* Wr, const float* Wi,
                                           int lane) {
  fft4_fwd(vr, vi);
#pragma unroll
  for (int b = 1; b < 4; ++b) {
    float ar = vr[b], ai = vi[b];
    vr[b] = ar * twFr[b-1] - ai * twFi[b-1];
    vi[b] = ar * twFi[b-1] + ai * twFr[b-1];
  }
#pragma unroll
  for (int s = 0; s < 6; ++s) {
    const int h = 32 >> s;
    const bool hi = (lane & h) != 0;
    const float sg = hi ? -1.0f : 1.0f;
#pragma unroll
    for (int b = 0; b < 4; ++b) {
      float pr = __shfl_xor(vr[b], h, 64);
      float pi = __shfl_xor(vi[b], h, 64);
      float tr = fmaf(sg, vr[b], pr);
      float ti = fmaf(sg, vi[b], pi);
      float mr = tr * Wr[s] - ti * Wi[s];
      float mi = tr * Wi[s] + ti * Wr[s];
      vr[b] = hi ? mr : tr;
      vi[b] = hi ? mi : ti;
    }
  }
}

__device__ __forceinline__ void ifft256(float* vr, float* vi,
                                        const float* twFr, const float* twFi,
                                        const float* Wr, const float* Wi,
                                        int lane) {
#pragma unroll
  for (int s = 5; s >= 0; --s) {
    const int h = 32 >> s;
    const bool hi = (lane & h) != 0;
    const float sg = hi ? -1.0f : 1.0f;
#pragma unroll
    for (int b = 0; b < 4; ++b) {
      float pr = __shfl_xor(vr[b], h, 64);
      float pi = __shfl_xor(vi[b], h, 64);
      float qr = hi ? vr[b] : pr;
      float qi = hi ? vi[b] : pi;
      float rr = hi ? pr : vr[b];
      float ri = hi ? pi : vi[b];
      float tr = fmaf(Wr[s], qr,  Wi[s] * qi);
      float ti = fmaf(Wr[s], qi, -(Wi[s] * qr));
      vr[b] = fmaf(sg, tr, rr);
      vi[b] = fmaf(sg, ti, ri);
    }
  }
#pragma unroll
  for (int b = 1; b < 4; ++b) {          // conj twiddle
    float ar = vr[b], ai = vi[b];
    vr[b] = ar * twFr[b-1] + ai * twFi[b-1];
    vi[b] = ai * twFr[b-1] - ar * twFi[b-1];
  }
  fft4_inv(vr, vi);
}

// Half-spectrum S[0..255] (+ real scalar S256 = bin 256) -> packed Z for
// ifft256 (real-signal trick): A=(S[k]+S[k+256])/2, B=W^{-k}(S[k]-S[k+256])/2,
// Z = A + iB, with S[k+256] = conj(S[256-k]). twH[b] = e^{+2pi i k/512}.
__device__ __forceinline__ void half_to_z(float* Sr, float* Si, float S256,
                                          const float* twHr, const float* twHi,
                                          int lane, int pl0, int plx) {
  float Pr[4], Pi[4];
  Pr[0] = __shfl(Sr[0], pl0, 64); Pi[0] = __shfl(Si[0], pl0, 64);
#pragma unroll
  for (int b = 1; b < 4; ++b) {
    Pr[b] = __shfl(Sr[4 - b], plx, 64);
    Pi[b] = __shfl(Si[4 - b], plx, 64);
  }
  if (lane == 0) { Pr[0] = S256; Pi[0] = 0.0f; }   // k=0 pairs with bin 256
#pragma unroll
  for (int b = 0; b < 4; ++b) {
    float Ar = 0.5f * (Sr[b] + Pr[b]);
    float Ai = 0.5f * (Si[b] - Pi[b]);
    float Br = 0.5f * (Sr[b] - Pr[b]);
    float Bi = 0.5f * (Si[b] + Pi[b]);
    float Brr = Br * twHr[b] - Bi * twHi[b];
    float Bii = Br * twHi[b] + Bi * twHr[b];
    Sr[b] = Ar - Bii;
    Si[b] = Ai + Brr;
  }
}

// Per-bin mode update exploiting Hermitian symmetry (no cross-lane ops):
//   U[k] = (X-Uo)[k]*(g+ + g-)/2 + (lam[k+256]*g+ + lam[256-k]*g-)/4
__device__ __forceinline__ void mode_update4(const float* Xr, const float* Xi,
                                             const float* Vr, const float* Vi,
                                             float* Ur, float* Ui,
                                             const float* lam1, const float* lam2,
                                             float om, float f0) {
#pragma unroll
  for (int b = 0; b < 4; ++b) {
    float f = f0 + (float)b * (1.0f / 512.0f);
    float dfp = f - om;
    float dfm = f + om;    // (-f-om)^2 == (f+om)^2
    float gp = __builtin_amdgcn_rcpf(fmaf(1600.0f * dfp, dfp, 1.0f));
    float gm = __builtin_amdgcn_rcpf(fmaf(1600.0f * dfm, dfm, 1.0f));
    float gs = 0.5f * (gp + gm);
    float Dr = Xr[b] - Vr[b], Di = Xi[b] - Vi[b];
    float lt = 0.25f * fmaf(lam1[b], gp, lam2[b] * gm);
    Ur[b] = fmaf(Dr, gs, lt);
    Ui[b] = Di * gs;
  }
}

// One wave per (b,d) sequence; half-spectrum state (4 bins/lane + bin-256
// scalar). Lambda time-domain: register accumulators + LDS copy at
// psi(p) = 128*(p&3) + (p>>2) (all access patterns <=2-way bank aliasing).
__global__ __attribute__((amdgpu_flat_work_group_size(256, 256),
                          amdgpu_waves_per_eu(4, 4)))
void vmd_kernel(const float* __restrict__ x, float* __restrict__ out) {
  __shared__ float stage[4 * 512];    // [seq][n] transpose buffer (in & out)
  __shared__ float ldsLam[4 * 512];   // psi-permuted lambda per wave

  const int tid = threadIdx.x;
  const int wv = tid >> 6;
  const int lane = tid & 63;
  const int w = (blockIdx.x >> 3) + ((blockIdx.x & 7) << 7);   // XCD swizzle
  const int g = 4 * w + wv;
  const int bb = w >> 5;
  const int d0 = (4 * w) & 127;
  const int base4 = bb * 16384 + (d0 >> 2);
  float* lamLds = ldsLam + wv * 512;

  const int rev = (int)(__brev((unsigned)lane) >> 26);           // rev6(lane)
  const float f0 = (float)rev * (1.0f / 128.0f);                 // 4*rev/512
  const int plx = lane ^ 63;                                     // b>=1 partner
  const int pl0 = (int)(__brev((unsigned)((64 - rev) & 63)) >> 26); // b==0 partner

  // FFT64 stage twiddles
  float Wr[6], Wi[6];
#pragma unroll
  for (int s = 0; s < 6; ++s) {
    const int h = 32 >> s;
    float th = (float)(lane & (h - 1)) * (3.14159265358979323846f / (float)h);
    float sn, cs; sincosf(th, &sn, &cs);
    Wr[s] = cs; Wi[s] = -sn;
  }
  // twF[b-1] = e^{-2pi i lane b / 256}, b=1..3
  float twFr[3], twFi[3];
#pragma unroll
  for (int b = 1; b < 4; ++b) {
    float th = (float)(lane * b) * 0.02454369260617026f;   // 2pi/256
    float sn, cs; sincosf(th, &sn, &cs);
    twFr[b-1] = cs; twFi[b-1] = -sn;
  }
  // twH[b] = e^{+2pi i k/512}, k = 4*rev+b
  float twHr[4], twHi[4];
#pragma unroll
  for (int b = 0; b < 4; ++b) {
    float th = (float)(4 * rev + b) * 0.01227184630308513f; // 2pi/512
    float sn, cs; sincosf(th, &sn, &cs);
    twHr[b] = cs; twHi[b] = sn;
  }

  // ---- load x: float4 (n, d0..d0+3) -> stage[seq][n]; zero lambda ----
  {
    const float4* x4 = (const float4*)x;
    float4 va = x4[base4 + tid * 32];
    float4 vb = x4[base4 + (tid + 256) * 32];
    stage[tid]        = va.x; stage[512 + tid]        = va.y;
    stage[1024 + tid] = va.z; stage[1536 + tid]       = va.w;
    stage[tid + 256]        = vb.x; stage[512 + tid + 256]  = vb.y;
    stage[1024 + tid + 256] = vb.z; stage[1536 + tid + 256] = vb.w;
#pragma unroll
    for (int j = 0; j < 8; ++j) ldsLam[tid * 8 + j] = 0.0f;
  }
  __syncthreads();

  // ---- x in packed layout: xE[a]=x[128a+2lane], xO[a]=x[128a+2lane+1] ----
  float xE[4], xO[4];
  float zr[4], zi[4];
#pragma unroll
  for (int a = 0; a < 4; ++a) {
    xE[a] = stage[wv * 512 + 128 * a + 2 * lane];
    xO[a] = stage[wv * 512 + 128 * a + 2 * lane + 1];
    zr[a] = xE[a]; zi[a] = xO[a];
  }
  // Forward real-FFT trick: Z = fft256(xE + i*xO) -> X half-spectrum + X256
  fft256_fwd(zr, zi, twFr, twFi, Wr, Wi, lane);
  float Xr[4], Xi[4], X256;
  {
    float Pr[4], Pi[4];
    Pr[0] = __shfl(zr[0], pl0, 64); Pi[0] = __shfl(zi[0], pl0, 64);
#pragma unroll
    for (int b = 1; b < 4; ++b) {
      Pr[b] = __shfl(zr[4 - b], plx, 64);
      Pi[b] = __shfl(zi[4 - b], plx, 64);
    }
    X256 = __shfl(zr[0] - zi[0], 0, 64);   // E[0]-O[0]
#pragma unroll
    for (int b = 0; b < 4; ++b) {
      float Er = 0.5f * (zr[b] + Pr[b]);
      float Ei = 0.5f * (zi[b] - Pi[b]);
      float Or = 0.5f * (zi[b] + Pi[b]);
      float Oi = -0.5f * (zr[b] - Pr[b]);
      // X = E + conj(twH)*O
      Xr[b] = Er + Or * twHr[b] + Oi * twHi[b];
      Xi[b] = Ei + Oi * twHr[b] - Or * twHi[b];
    }
  }

  float U0r[4], U0i[4], U1r[4], U1i[4], lamE[4], lamO[4];
#pragma unroll
  for (int b = 0; b < 4; ++b) {
    U0r[b] = 0.0f; U0i[b] = 0.0f; U1r[b] = 0.0f; U1i[b] = 0.0f;
    lamE[b] = 0.0f; lamO[b] = 0.0f;
  }
  float U0_256 = 0.0f, U1_256 = 0.0f;
  float om0 = 0.0f, om1 = 0.0f;

  const int psiE = 256 * (lane & 1) + (lane >> 1);   // lambda write base

#pragma unroll 1
  for (int it = 0; it < 50; ++it) {
    // lambda reads (psi layout): lam1[b]=lam[k+256], lam2[b]=lam[256-k], lam[0]
    float lam1[4], lam2[4];
#pragma unroll
    for (int b = 0; b < 4; ++b) lam1[b] = lamLds[128 * b + 64 + rev];
    lam2[0] = lamLds[64 - rev];
#pragma unroll
    for (int b = 1; b < 4; ++b) lam2[b] = lamLds[128 * (4 - b) + 63 - rev];
    float lam0 = lamLds[0];

    mode_update4(Xr, Xi, U1r, U1i, U0r, U0i, lam1, lam2, om0, f0);
    {
      float dm = 0.5f + om0;
      float gg = __builtin_amdgcn_rcpf(fmaf(1600.0f * dm, dm, 1.0f));
      U0_256 = (X256 - U1_256 + 0.5f * lam0) * gg;
    }
    mode_update4(Xr, Xi, U0r, U0i, U1r, U1i, lam1, lam2, om1, f0);
    {
      float dm = 0.5f + om1;
      float gg = __builtin_amdgcn_rcpf(fmaf(1600.0f * dm, dm, 1.0f));
      U1_256 = (X256 - U0_256 + 0.5f * lam0) * gg;
    }

    // omega: all stored bins are positive freqs (bin 256 excluded by mask)
    float n0 = 0.0f, d0s = 0.0f, n1 = 0.0f, d1 = 0.0f;
#pragma unroll
    for (int b = 0; b < 4; ++b) {
      float f = f0 + (float)b * (1.0f / 512.0f);
      float p0 = fmaf(U0r[b], U0r[b], U0i[b] * U0i[b]);
      float p1 = fmaf(U1r[b], U1r[b], U1i[b] * U1i[b]);
      n0 = fmaf(f, p0, n0); d0s += p0;
      n1 = fmaf(f, p1, n1); d1 += p1;
    }
#pragma unroll
    for (int off = 32; off >= 1; off >>= 1) {
      n0 += __shfl_xor(n0, off, 64);
      d0s += __shfl_xor(d0s, off, 64);
      n1 += __shfl_xor(n1, off, 64);
      d1 += __shfl_xor(d1, off, 64);
    }
    om0 = n0 / (d0s + 1e-7f);
    om1 = n1 / (d1 + 1e-7f);

    if (it < 49) {   // last iteration's lambda is never consumed
#pragma unroll
      for (int b = 0; b < 4; ++b) { zr[b] = U0r[b] + U1r[b]; zi[b] = U0i[b] + U1i[b]; }
      float S256 = U0_256 + U1_256;
      half_to_z(zr, zi, S256, twHr, twHi, lane, pl0, plx);
      ifft256(zr, zi, twFr, twFi, Wr, Wi, lane);
      // u[128a+2lane] = Re z / 256, u[..+1] = Im z / 256
#pragma unroll
      for (int a = 0; a < 4; ++a) {
        lamE[a] = fmaf(0.001f, xE[a] - zr[a] * (1.0f / 256.0f), lamE[a]);
        lamO[a] = fmaf(0.001f, xO[a] - zi[a] * (1.0f / 256.0f), lamO[a]);
        lamLds[psiE + 32 * a]       = lamE[a];
        lamLds[psiE + 32 * a + 128] = lamO[a];
      }
      asm volatile("s_waitcnt lgkmcnt(0)" ::: "memory");
    }
  }

  // ---- final modes: half->z, ifft256, unpack to stage, float4 stores ----
  float4* o4 = (float4*)out;
#pragma unroll
  for (int b = 0; b < 4; ++b) { zr[b] = U0r[b]; zi[b] = U0i[b]; }
  half_to_z(zr, zi, U0_256, twHr, twHi, lane, pl0, plx);
  ifft256(zr, zi, twFr, twFi, Wr, Wi, lane);
  __syncthreads();   // (stage-x no longer needed; regs hold xE/xO)
#pragma unroll
  for (int a = 0; a < 4; ++a) {
    stage[wv * 512 + 128 * a + 2 * lane]     = zr[a] * (1.0f / 256.0f);
    stage[wv * 512 + 128 * a + 2 * lane + 1] = zi[a] * (1.0f / 256.0f);
  }
  __syncthreads();
#pragma unroll
  for (int r = 0; r < 2; ++r) {
    const int n = tid + r * 256;
    float4 v;
    v.x = stage[n]; v.y = stage[512 + n]; v.z = stage[1024 + n]; v.w = stage[1536 + n];
    o4[FIELD / 4 + base4 + n * 32] = v;
  }
  __syncthreads();
#pragma unroll
  for (int b = 0; b < 4; ++b) { zr[b] = U1r[b]; zi[b] = U1i[b]; }
  half_to_z(zr, zi, U1_256, twHr, twHi, lane, pl0, plx);
  ifft256(zr, zi, twFr, twFi, Wr, Wi, lane);
#pragma unroll
  for (int a = 0; a < 4; ++a) {
    stage[wv * 512 + 128 * a + 2 * lane]     = zr[a] * (1.0f / 256.0f);
    stage[wv * 512 + 128 * a + 2 * lane + 1] = zi[a] * (1.0f / 256.0f);
  }
  __syncthreads();
#pragma unroll
  for (int r = 0; r < 2; ++r) {
    const int n = tid + r * 256;
    float4 v;
    v.x = stage[n]; v.y = stage[512 + n]; v.z = stage[1024 + n]; v.w = stage[1536 + n];
    o4[2 * FIELD / 4 + base4 + n * 32] = v;
  }

  if (lane == 0) {
    out[g] = om0;            // staged in trend region (zeroed later)
    out[NSEQ + g] = om1;
  }
}

__global__ __launch_bounds__(128) void order_kernel(float* __restrict__ out) {
  const int bb = blockIdx.x;
  const int dd = threadIdx.x;
  float o0 = out[bb * 128 + dd];
  float o1 = out[NSEQ + bb * 128 + dd];
#pragma unroll
  for (int off = 32; off >= 1; off >>= 1) {
    o0 += __shfl_down(o0, off);
    o1 += __shfl_down(o1, off);
  }
  __shared__ float s0[2], s1[2];
  const int wv = dd >> 6;
  if ((dd & 63) == 0) { s0[wv] = o0; s1[wv] = o1; }
  __syncthreads();
  if (dd == 0) {
    const float a = s0[0] + s0[1];
    const float c = s1[0] + s1[1];
    out[2 * NSEQ + bb] = (a > c) ? 1.0f : 0.0f;
  }
}

__global__ __launch_bounds__(256) void swap_kernel(float* __restrict__ out) {
  const int idx = blockIdx.x * 256 + threadIdx.x;
  const int bb = idx >> 16;
  const float flag = out[2 * NSEQ + bb];
  if (flag > 0.5f) {
    const float p = out[FIELD + idx];
    const float r = out[2 * FIELD + idx];
    out[FIELD + idx] = r;
    out[2 * FIELD + idx] = p;
  }
}

extern "C" void kernel_launch(void* const* d_in, const int* in_sizes, int n_in,
                              void* d_out, int out_size, void* d_ws, size_t ws_size,
                              hipStream_t stream) {
  (void)in_sizes; (void)n_in; (void)d_ws; (void)ws_size; (void)out_size;
  const float* x = (const float*)d_in[0];
  float* out = (float*)d_out;
  vmd_kernel<<<NSEQ / 4, 256, 0, stream>>>(x, out);
  order_kernel<<<32, 128, 0, stream>>>(out);
  swap_kernel<<<FIELD / 256, 256, 0, stream>>>(out);
  hipMemsetAsync(out, 0, (size_t)FIELD * sizeof(float), stream);
}

// Round 8
// 329.581 us; speedup vs baseline: 2.1702x; 1.0719x over previous
//
#include <hip/hip_runtime.h>
#include <math.h>

#define FIELD 2097152   // 32*512*128
#define NSEQ  4096      // 32*128 sequences

typedef float f2 __attribute__((ext_vector_type(2)));   // (re, im) -> VGPR pair

__device__ __forceinline__ f2 cmuli(f2 a)  { return (f2){-a.y, a.x}; }  //  i*a
__device__ __forceinline__ f2 cmulni(f2 a) { return (f2){a.y, -a.x}; }  // -i*a
__device__ __forceinline__ f2 conjf2(f2 a) { return (f2){a.x, -a.y}; }
// a * (c + i s)
__device__ __forceinline__ f2 cmul(f2 a, float c, float s) {
  return c * a + s * cmuli(a);
}
// a * (c - i s)
__device__ __forceinline__ f2 cmulc(f2 a, float c, float s) {
  return c * a - s * cmuli(a);
}
__device__ __forceinline__ f2 shflx2(f2 v, int h) {
  return (f2){__shfl_xor(v.x, h, 64), __shfl_xor(v.y, h, 64)};
}
__device__ __forceinline__ f2 shfl2(f2 v, int l) {
  return (f2){__shfl(v.x, l, 64), __shfl(v.y, l, 64)};
}

// ---------------------------------------------------------------------------
// DFT4 over the lane's 4 register slots (packed complex).
// ---------------------------------------------------------------------------
__device__ __forceinline__ void fft4_fwd(f2* v) {
  f2 t0 = v[0] + v[2], t1 = v[0] - v[2];
  f2 t2 = v[1] + v[3], t3 = v[1] - v[3];
  v[0] = t0 + t2; v[2] = t0 - t2;
  v[1] = t1 + cmulni(t3);
  v[3] = t1 + cmuli(t3);
}
__device__ __forceinline__ void fft4_inv(f2* v) {
  f2 t0 = v[0] + v[2], t1 = v[0] - v[2];
  f2 t2 = v[1] + v[3], t3 = v[1] - v[3];
  v[0] = t0 + t2; v[2] = t0 - t2;
  v[1] = t1 + cmuli(t3);
  v[3] = t1 + cmulni(t3);
}

// 256-point FFT: time n = 64a+lane (slot a) <-> freq k = 4*rev6(lane)+b.
__device__ __forceinline__ void fft256_fwd(f2* v,
                                           const float* twFr, const float* twFi,
                                           const float* Wr, const float* Wi,
                                           int lane) {
  fft4_fwd(v);
#pragma unroll
  for (int b = 1; b < 4; ++b) v[b] = cmul(v[b], twFr[b-1], twFi[b-1]);
#pragma unroll
  for (int s = 0; s < 6; ++s) {
    const int h = 32 >> s;
    const bool hi = (lane & h) != 0;
    const float sg = hi ? -1.0f : 1.0f;
#pragma unroll
    for (int b = 0; b < 4; ++b) {
      f2 p = shflx2(v[b], h);
      f2 t = sg * v[b] + p;
      f2 m = cmul(t, Wr[s], Wi[s]);
      v[b] = hi ? m : t;
    }
  }
}

__device__ __forceinline__ void ifft256(f2* v,
                                        const float* twFr, const float* twFi,
                                        const float* Wr, const float* Wi,
                                        int lane) {
#pragma unroll
  for (int s = 5; s >= 0; --s) {
    const int h = 32 >> s;
    const bool hi = (lane & h) != 0;
    const float sg = hi ? -1.0f : 1.0f;
#pragma unroll
    for (int b = 0; b < 4; ++b) {
      f2 p = shflx2(v[b], h);
      f2 q = hi ? v[b] : p;     // operand multiplied by conj(W)
      f2 r = hi ? p : v[b];     // operand added
      f2 t = cmulc(q, Wr[s], Wi[s]);
      v[b] = sg * t + r;
    }
  }
#pragma unroll
  for (int b = 1; b < 4; ++b) v[b] = cmulc(v[b], twFr[b-1], twFi[b-1]);
  fft4_inv(v);
}

// Half-spectrum S[0..255] (+ real scalar S256) -> packed Z for ifft256.
__device__ __forceinline__ void half_to_z(f2* S, float S256,
                                          const float* twHr, const float* twHi,
                                          int lane, int pl0, int plx) {
  f2 P[4];
  P[0] = shfl2(S[0], pl0);
#pragma unroll
  for (int b = 1; b < 4; ++b) P[b] = shfl2(S[4 - b], plx);
  P[0] = (lane == 0) ? (f2){S256, 0.0f} : P[0];
#pragma unroll
  for (int b = 0; b < 4; ++b) {
    f2 cP = conjf2(P[b]);
    f2 A = 0.5f * (S[b] + cP);
    f2 B = 0.5f * (S[b] - cP);
    f2 Bt = cmul(B, twHr[b], twHi[b]);
    S[b] = A + cmuli(Bt);
  }
}

// Per-bin mode update exploiting Hermitian symmetry (no cross-lane ops).
__device__ __forceinline__ void mode_update4(const f2* X, const f2* V, f2* U,
                                             const float* lam1, const float* lam2,
                                             float om, float f0) {
#pragma unroll
  for (int b = 0; b < 4; ++b) {
    float f = f0 + (float)b * (1.0f / 512.0f);
    float dfp = f - om;
    float dfm = f + om;
    float gp = __builtin_amdgcn_rcpf(fmaf(1600.0f * dfp, dfp, 1.0f));
    float gm = __builtin_amdgcn_rcpf(fmaf(1600.0f * dfm, dfm, 1.0f));
    float gs = 0.5f * (gp + gm);
    f2 D = X[b] - V[b];
    float lt = 0.25f * fmaf(lam1[b], gp, lam2[b] * gm);
    U[b] = gs * D + (f2){lt, 0.0f};
  }
}

// One wave per (b,d) sequence; half-spectrum state, packed-f32 complex math.
__global__ __attribute__((amdgpu_flat_work_group_size(256, 256),
                          amdgpu_waves_per_eu(4, 4)))
void vmd_kernel(const float* __restrict__ x, float* __restrict__ out) {
  __shared__ float stage[4 * 512];    // [seq][n] transpose buffer (in & out)
  __shared__ float ldsLam[4 * 512];   // psi-permuted lambda per wave

  const int tid = threadIdx.x;
  const int wv = tid >> 6;
  const int lane = tid & 63;
  const int w = (blockIdx.x >> 3) + ((blockIdx.x & 7) << 7);   // XCD swizzle
  const int g = 4 * w + wv;
  const int bb = w >> 5;
  const int d0 = (4 * w) & 127;
  const int base4 = bb * 16384 + (d0 >> 2);
  float* lamLds = ldsLam + wv * 512;

  const int rev = (int)(__brev((unsigned)lane) >> 26);           // rev6(lane)
  const float f0 = (float)rev * (1.0f / 128.0f);
  const int plx = lane ^ 63;
  const int pl0 = (int)(__brev((unsigned)((64 - rev) & 63)) >> 26);

  float Wr[6], Wi[6];
#pragma unroll
  for (int s = 0; s < 6; ++s) {
    const int h = 32 >> s;
    float th = (float)(lane & (h - 1)) * (3.14159265358979323846f / (float)h);
    float sn, cs; sincosf(th, &sn, &cs);
    Wr[s] = cs; Wi[s] = -sn;
  }
  float twFr[3], twFi[3];
#pragma unroll
  for (int b = 1; b < 4; ++b) {
    float th = (float)(lane * b) * 0.02454369260617026f;   // 2pi/256
    float sn, cs; sincosf(th, &sn, &cs);
    twFr[b-1] = cs; twFi[b-1] = -sn;
  }
  float twHr[4], twHi[4];
#pragma unroll
  for (int b = 0; b < 4; ++b) {
    float th = (float)(4 * rev + b) * 0.01227184630308513f; // 2pi/512
    float sn, cs; sincosf(th, &sn, &cs);
    twHr[b] = cs; twHi[b] = sn;
  }

  // ---- load x: float4 (n, d0..d0+3) -> stage[seq][n]; zero lambda ----
  {
    const float4* x4 = (const float4*)x;
    float4 va = x4[base4 + tid * 32];
    float4 vb = x4[base4 + (tid + 256) * 32];
    stage[tid]        = va.x; stage[512 + tid]        = va.y;
    stage[1024 + tid] = va.z; stage[1536 + tid]       = va.w;
    stage[tid + 256]        = vb.x; stage[512 + tid + 256]  = vb.y;
    stage[1024 + tid + 256] = vb.z; stage[1536 + tid + 256] = vb.w;
#pragma unroll
    for (int j = 0; j < 8; ++j) ldsLam[tid * 8 + j] = 0.0f;
  }
  __syncthreads();

  // ---- x packed: xv[a] = (x[128a+2lane], x[128a+2lane+1]) ----
  f2 xv[4], z[4];
#pragma unroll
  for (int a = 0; a < 4; ++a) {
    xv[a].x = stage[wv * 512 + 128 * a + 2 * lane];
    xv[a].y = stage[wv * 512 + 128 * a + 2 * lane + 1];
    z[a] = xv[a];
  }
  fft256_fwd(z, twFr, twFi, Wr, Wi, lane);
  f2 X[4];
  float X256;
  {
    f2 P[4];
    P[0] = shfl2(z[0], pl0);
#pragma unroll
    for (int b = 1; b < 4; ++b) P[b] = shfl2(z[4 - b], plx);
    X256 = __shfl(z[0].x - z[0].y, 0, 64);
#pragma unroll
    for (int b = 0; b < 4; ++b) {
      f2 cP = conjf2(P[b]);
      f2 E = 0.5f * (z[b] + cP);
      f2 O = 0.5f * cmulni(z[b] - cP);
      X[b] = E + cmulc(O, twHr[b], twHi[b]);
    }
  }

  f2 U0[4], U1[4], lam[4];
#pragma unroll
  for (int b = 0; b < 4; ++b) {
    U0[b] = (f2){0.0f, 0.0f}; U1[b] = (f2){0.0f, 0.0f};
    lam[b] = (f2){0.0f, 0.0f};
  }
  float U0_256 = 0.0f, U1_256 = 0.0f;
  float om0 = 0.0f, om1 = 0.0f;

  const int psiE = 256 * (lane & 1) + (lane >> 1);   // lambda write base

#pragma unroll 1
  for (int it = 0; it < 50; ++it) {
    // lambda reads (psi layout): lam1[b]=lam[k+256], lam2[b]=lam[256-k]
    float lam1[4], lam2[4];
#pragma unroll
    for (int b = 0; b < 4; ++b) lam1[b] = lamLds[128 * b + 64 + rev];
    lam2[0] = lamLds[64 - rev];
#pragma unroll
    for (int b = 1; b < 4; ++b) lam2[b] = lamLds[128 * (4 - b) + 63 - rev];
    float lam0 = lamLds[0];

    mode_update4(X, U1, U0, lam1, lam2, om0, f0);
    {
      float dm = 0.5f + om0;
      float gg = __builtin_amdgcn_rcpf(fmaf(1600.0f * dm, dm, 1.0f));
      U0_256 = (X256 - U1_256 + 0.5f * lam0) * gg;
    }
    mode_update4(X, U0, U1, lam1, lam2, om1, f0);
    {
      float dm = 0.5f + om1;
      float gg = __builtin_amdgcn_rcpf(fmaf(1600.0f * dm, dm, 1.0f));
      U1_256 = (X256 - U0_256 + 0.5f * lam0) * gg;
    }

    // omega: all stored bins are positive freqs
    float n0 = 0.0f, d0s = 0.0f, n1 = 0.0f, d1 = 0.0f;
#pragma unroll
    for (int b = 0; b < 4; ++b) {
      float f = f0 + (float)b * (1.0f / 512.0f);
      float p0 = fmaf(U0[b].x, U0[b].x, U0[b].y * U0[b].y);
      float p1 = fmaf(U1[b].x, U1[b].x, U1[b].y * U1[b].y);
      n0 = fmaf(f, p0, n0); d0s += p0;
      n1 = fmaf(f, p1, n1); d1 += p1;
    }
#pragma unroll
    for (int off = 32; off >= 1; off >>= 1) {
      n0 += __shfl_xor(n0, off, 64);
      d0s += __shfl_xor(d0s, off, 64);
      n1 += __shfl_xor(n1, off, 64);
      d1 += __shfl_xor(d1, off, 64);
    }
    om0 = n0 / (d0s + 1e-7f);
    om1 = n1 / (d1 + 1e-7f);

    if (it < 49) {   // last iteration's lambda is never consumed
#pragma unroll
      for (int b = 0; b < 4; ++b) z[b] = U0[b] + U1[b];
      float S256 = U0_256 + U1_256;
      half_to_z(z, S256, twHr, twHi, lane, pl0, plx);
      ifft256(z, twFr, twFi, Wr, Wi, lane);
#pragma unroll
      for (int a = 0; a < 4; ++a) {
        lam[a] = lam[a] + 0.001f * (xv[a] - z[a] * (1.0f / 256.0f));
        lamLds[psiE + 32 * a]       = lam[a].x;
        lamLds[psiE + 32 * a + 128] = lam[a].y;
      }
      asm volatile("s_waitcnt lgkmcnt(0)" ::: "memory");
    }
  }

  // ---- final modes: half->z, ifft256, unpack to stage, float4 stores ----
  float4* o4 = (float4*)out;
#pragma unroll
  for (int b = 0; b < 4; ++b) z[b] = U0[b];
  half_to_z(z, U0_256, twHr, twHi, lane, pl0, plx);
  ifft256(z, twFr, twFi, Wr, Wi, lane);
  __syncthreads();
#pragma unroll
  for (int a = 0; a < 4; ++a) {
    stage[wv * 512 + 128 * a + 2 * lane]     = z[a].x * (1.0f / 256.0f);
    stage[wv * 512 + 128 * a + 2 * lane + 1] = z[a].y * (1.0f / 256.0f);
  }
  __syncthreads();
#pragma unroll
  for (int r = 0; r < 2; ++r) {
    const int n = tid + r * 256;
    float4 v;
    v.x = stage[n]; v.y = stage[512 + n]; v.z = stage[1024 + n]; v.w = stage[1536 + n];
    o4[FIELD / 4 + base4 + n * 32] = v;
  }
  __syncthreads();
#pragma unroll
  for (int b = 0; b < 4; ++b) z[b] = U1[b];
  half_to_z(z, U1_256, twHr, twHi, lane, pl0, plx);
  ifft256(z, twFr, twFi, Wr, Wi, lane);
#pragma unroll
  for (int a = 0; a < 4; ++a) {
    stage[wv * 512 + 128 * a + 2 * lane]     = z[a].x * (1.0f / 256.0f);
    stage[wv * 512 + 128 * a + 2 * lane + 1] = z[a].y * (1.0f / 256.0f);
  }
  __syncthreads();
#pragma unroll
  for (int r = 0; r < 2; ++r) {
    const int n = tid + r * 256;
    float4 v;
    v.x = stage[n]; v.y = stage[512 + n]; v.z = stage[1024 + n]; v.w = stage[1536 + n];
    o4[2 * FIELD / 4 + base4 + n * 32] = v;
  }

  if (lane == 0) {
    out[g] = om0;            // staged in trend region (zeroed later)
    out[NSEQ + g] = om1;
  }
}

__global__ __launch_bounds__(128) void order_kernel(float* __restrict__ out) {
  const int bb = blockIdx.x;
  const int dd = threadIdx.x;
  float o0 = out[bb * 128 + dd];
  float o1 = out[NSEQ + bb * 128 + dd];
#pragma unroll
  for (int off = 32; off >= 1; off >>= 1) {
    o0 += __shfl_down(o0, off);
    o1 += __shfl_down(o1, off);
  }
  __shared__ float s0[2], s1[2];
  const int wv = dd >> 6;
  if ((dd & 63) == 0) { s0[wv] = o0; s1[wv] = o1; }
  __syncthreads();
  if (dd == 0) {
    const float a = s0[0] + s0[1];
    const float c = s1[0] + s1[1];
    out[2 * NSEQ + bb] = (a > c) ? 1.0f : 0.0f;
  }
}

__global__ __launch_bounds__(256) void swap_kernel(float* __restrict__ out) {
  const int idx = blockIdx.x * 256 + threadIdx.x;
  const int bb = idx >> 16;
  const float flag = out[2 * NSEQ + bb];
  if (flag > 0.5f) {
    const float p = out[FIELD + idx];
    const float r = out[2 * FIELD + idx];
    out[FIELD + idx] = r;
    out[2 * FIELD + idx] = p;
  }
}

extern "C" void kernel_launch(void* const* d_in, const int* in_sizes, int n_in,
                              void* d_out, int out_size, void* d_ws, size_t ws_size,
                              hipStream_t stream) {
  (void)in_sizes; (void)n_in; (void)d_ws; (void)ws_size; (void)out_size;
  const float* x = (const float*)d_in[0];
  float* out = (float*)d_out;
  vmd_kernel<<<NSEQ / 4, 256, 0, stream>>>(x, out);
  order_kernel<<<32, 128, 0, stream>>>(out);
  swap_kernel<<<FIELD / 256, 256, 0, stream>>>(out);
  hipMemsetAsync(out, 0, (size_t)FIELD * sizeof(float), stream);
}